// Round 2
// 2728.139 us; speedup vs baseline: 1.0090x; 1.0090x over previous
//
#include <hip/hip_runtime.h>
#include <math.h>

#define N_NODES 200000
#define N_EDGES 3200000
#define NB      128
#define FIN     768
#define FH      64      // HID == OUT == 64
#define NC      4

#define SCAN_TILE 1024                      // 256 threads x 4 elems
#define NBLK ((N_NODES + SCAN_TILE - 1) / SCAN_TILE)   // 196 (<=256 required)

// ---------------------------------------------------------------------------
// Integer in-degree of dst for both edge sets. degi[0..N)=td, [N..2N)=bu.
__global__ __launch_bounds__(256) void k_degi(const int* __restrict__ dst_td,
                                              const int* __restrict__ dst_bu,
                                              int* __restrict__ degi) {
    int i = blockIdx.x * blockDim.x + threadIdx.x;
    if (i < N_EDGES) {
        atomicAdd(degi + dst_td[i], 1);
        atomicAdd(degi + N_NODES + dst_bu[i], 1);
    }
}

// dinv = rsqrt(deg + 1)   (self-loop included; always > 0)
__global__ __launch_bounds__(256) void k_dinv(const int* __restrict__ degi,
                                              float* __restrict__ dv) {
    int i = blockIdx.x * blockDim.x + threadIdx.x;
    if (i < 2 * N_NODES) dv[i] = rsqrtf((float)degi[i] + 1.0f);
}

// ---------------------------------------------------------------------------
// Prefix-scan of degrees -> rowptr (exclusive), cursor (copy of rowptr).
__global__ __launch_bounds__(256) void k_scanA(const int* __restrict__ deg,
                                               int* __restrict__ bsum) {
    __shared__ int sh[256];
    int t = threadIdx.x, b = blockIdx.x;
    int base = b * SCAN_TILE + t * 4;
    int s = 0;
#pragma unroll
    for (int j = 0; j < 4; ++j) {
        int idx = base + j;
        if (idx < N_NODES) s += deg[idx];
    }
    sh[t] = s;
    __syncthreads();
    for (int off = 128; off > 0; off >>= 1) {
        if (t < off) sh[t] += sh[t + off];
        __syncthreads();
    }
    if (t == 0) bsum[b] = sh[0];
}

__global__ __launch_bounds__(256) void k_scanB(const int* __restrict__ bsum,
                                               int* __restrict__ boff) {
    __shared__ int sh[256];
    int t = threadIdx.x;
    int v = (t < NBLK) ? bsum[t] : 0;
    sh[t] = v;
    __syncthreads();
    for (int off = 1; off < 256; off <<= 1) {
        int a = (t >= off) ? sh[t - off] : 0;
        __syncthreads();
        sh[t] += a;
        __syncthreads();
    }
    if (t < NBLK) boff[t] = sh[t] - v;   // exclusive
}

__global__ __launch_bounds__(256) void k_scanC(const int* __restrict__ deg,
                                               const int* __restrict__ boff,
                                               int* __restrict__ rowptr,
                                               int* __restrict__ cursor) {
    __shared__ int sh[256];
    int t = threadIdx.x, b = blockIdx.x;
    int base = b * SCAN_TILE + t * 4;
    int v[4];
    int tot = 0;
#pragma unroll
    for (int j = 0; j < 4; ++j) {
        int idx = base + j;
        v[j] = (idx < N_NODES) ? deg[idx] : 0;
        tot += v[j];
    }
    sh[t] = tot;
    __syncthreads();
    for (int off = 1; off < 256; off <<= 1) {
        int a = (t >= off) ? sh[t - off] : 0;
        __syncthreads();
        sh[t] += a;
        __syncthreads();
    }
    int run = boff[b] + sh[t] - tot;     // global exclusive prefix at base
#pragma unroll
    for (int j = 0; j < 4; ++j) {
        int idx = base + j;
        if (idx < N_NODES) {
            rowptr[idx] = run;
            cursor[idx] = run;
            run += v[j];
        }
    }
    if (b == 0 && t == 0) rowptr[N_NODES] = N_EDGES;
}

// Counting-sort edges into CSR by dst (order within a row is arbitrary).
__global__ __launch_bounds__(256) void k_fill(const int* __restrict__ src,
                                              const int* __restrict__ dst,
                                              int* __restrict__ cursor,
                                              int* __restrict__ csr) {
    int e = blockIdx.x * blockDim.x + threadIdx.x;
    if (e < N_EDGES) {
        int d = dst[e];
        int pos = atomicAdd(cursor + d, 1);
        csr[pos] = src[e];
    }
}

// ---------------------------------------------------------------------------
// GEMM1: XWtd = dinvtd[i] * (x @ W1_td),  XWbu = dinvbu[i] * (x @ W1_bu)
// 128x128 tile, 256 threads, 8x8 per thread (2x2 quads of 4x4, +-64 split).
// As is k-major with XOR swizzle row^=((k>>2)&3)<<3 to kill transpose-write
// bank conflicts while keeping b128 reads aligned.
#define FMA4(A, s, W) \
    A.x = fmaf(s, W.x, A.x); A.y = fmaf(s, W.y, A.y); \
    A.z = fmaf(s, W.z, A.z); A.w = fmaf(s, W.w, A.w)

__global__ __launch_bounds__(256) void k_gemm1(const float* __restrict__ x,
                                               const float* __restrict__ Wtd,
                                               const float* __restrict__ Wbu,
                                               const float* __restrict__ dinvtd,
                                               const float* __restrict__ dinvbu,
                                               float* __restrict__ XWtd,
                                               float* __restrict__ XWbu) {
    __shared__ __align__(16) float As[32][128];   // [k][row] swizzled
    __shared__ __align__(16) float Ws[32][128];   // [k][col] (td | bu)
    const int tid  = threadIdx.x;
    const int row0 = blockIdx.x * 128;
    const int tx = tid & 15, ty = tid >> 4;
    const int c0 = tx * 4;               // col quad (0..60)
    const int r0 = ty * 4;               // row quad (0..60)
    const int a_kc  = tid & 7;           // k float4-chunk 0..7
    const int a_row = tid >> 3;          // 0..31 (+32p)
    const int w_cc  = tid & 31;          // col chunk 0..31
    const int w_k   = tid >> 5;          // 0..7 (+8p)
    const int a_sw  = (a_kc & 3) << 3;   // write swizzle (bits 3-4)

    float4 acc[2][4][2];
#pragma unroll
    for (int a = 0; a < 2; ++a)
#pragma unroll
        for (int b = 0; b < 4; ++b)
#pragma unroll
            for (int c = 0; c < 2; ++c) acc[a][b][c] = make_float4(0.f, 0.f, 0.f, 0.f);

    for (int k0 = 0; k0 < FIN; k0 += 32) {
        float4 xv[4], wv[4];
#pragma unroll
        for (int p = 0; p < 4; ++p) {
            int grow = row0 + a_row + 32 * p;
            if (grow > N_NODES - 1) grow = N_NODES - 1;     // clamp tail (stores guarded)
            xv[p] = *(const float4*)(x + (size_t)grow * FIN + k0 + a_kc * 4);
        }
#pragma unroll
        for (int p = 0; p < 4; ++p) {
            int kw = w_k + 8 * p;
            const float* Wp = (w_cc < 16) ? (Wtd + (size_t)(k0 + kw) * 64 + w_cc * 4)
                                          : (Wbu + (size_t)(k0 + kw) * 64 + w_cc * 4 - 64);
            wv[p] = *(const float4*)Wp;
        }
        __syncthreads();                 // previous tile fully consumed
        {
            int sr = a_row ^ a_sw;
#pragma unroll
            for (int p = 0; p < 4; ++p) {
                int srow = sr + 32 * p;                     // +32p doesn't touch bits 3-4
                As[a_kc * 4 + 0][srow] = xv[p].x;
                As[a_kc * 4 + 1][srow] = xv[p].y;
                As[a_kc * 4 + 2][srow] = xv[p].z;
                As[a_kc * 4 + 3][srow] = xv[p].w;
            }
#pragma unroll
            for (int p = 0; p < 4; ++p)
                *(float4*)&Ws[w_k + 8 * p][w_cc * 4] = wv[p];
        }
        __syncthreads();

#pragma unroll 8
        for (int kk = 0; kk < 32; ++kk) {
            int sw = ((kk >> 2) & 3) << 3;
            int ra = r0 ^ sw;
            float4 a0 = *(const float4*)&As[kk][ra];
            float4 a1 = *(const float4*)&As[kk][ra + 64];
            float4 w0 = *(const float4*)&Ws[kk][c0];
            float4 w1 = *(const float4*)&Ws[kk][c0 + 64];
            FMA4(acc[0][0][0], a0.x, w0); FMA4(acc[0][0][1], a0.x, w1);
            FMA4(acc[0][1][0], a0.y, w0); FMA4(acc[0][1][1], a0.y, w1);
            FMA4(acc[0][2][0], a0.z, w0); FMA4(acc[0][2][1], a0.z, w1);
            FMA4(acc[0][3][0], a0.w, w0); FMA4(acc[0][3][1], a0.w, w1);
            FMA4(acc[1][0][0], a1.x, w0); FMA4(acc[1][0][1], a1.x, w1);
            FMA4(acc[1][1][0], a1.y, w0); FMA4(acc[1][1][1], a1.y, w1);
            FMA4(acc[1][2][0], a1.z, w0); FMA4(acc[1][2][1], a1.z, w1);
            FMA4(acc[1][3][0], a1.w, w0); FMA4(acc[1][3][1], a1.w, w1);
        }
        __syncthreads();
    }
#pragma unroll
    for (int rh = 0; rh < 2; ++rh)
#pragma unroll
        for (int i = 0; i < 4; ++i) {
            int rr = row0 + rh * 64 + r0 + i;
            if (rr < N_NODES) {
                float dtd = dinvtd[rr], dbu = dinvbu[rr];
                float4 v0 = acc[rh][i][0];
                float4 v1 = acc[rh][i][1];
                float4 o0 = make_float4(v0.x * dtd, v0.y * dtd, v0.z * dtd, v0.w * dtd);
                float4 o1 = make_float4(v1.x * dbu, v1.y * dbu, v1.z * dbu, v1.w * dbu);
                *(float4*)(XWtd + (size_t)rr * 64 + c0) = o0;
                *(float4*)(XWbu + (size_t)rr * 64 + c0) = o1;
            }
        }
}

// ---------------------------------------------------------------------------
// RB[b][c] = sum_k relu(root[b,k]) * W2[(64+k), c]  for both branches
__global__ __launch_bounds__(128) void k_rb(const float* __restrict__ root,
                                            const float* __restrict__ W2td,
                                            const float* __restrict__ W2bu,
                                            float* __restrict__ RBtd,
                                            float* __restrict__ RBbu) {
    int b = blockIdx.x;
    int c = threadIdx.x;                 // 0..127
    const float* W2 = (c < 64) ? W2td : W2bu;
    int cc = c & 63;
    const float* rp = root + (size_t)b * FIN;
    float s = 0.f;
    for (int k = 0; k < FIN; ++k) {
        float r = fmaxf(rp[k], 0.f);
        s = fmaf(r, W2[(size_t)(64 + k) * 64 + cc], s);
    }
    (c < 64 ? RBtd : RBbu)[b * 64 + cc] = s;
}

// ---------------------------------------------------------------------------
// CSR gather over PRE-SCALED inputs (xws[i] = dinv[i] * xw[i]):
//   out[i] = bias + dinv[i] * (xws[i] + sum_e xws[src])
// quarter-wave (16 lanes x float4) per node, edge loop unrolled x4 for MLP.
__global__ __launch_bounds__(256) void k_gather(const int* __restrict__ rowptr,
                                                const int* __restrict__ csr,
                                                const float* __restrict__ dinv,
                                                const float* __restrict__ xws,
                                                const float* __restrict__ bias,
                                                float* __restrict__ out) {
    int t    = blockIdx.x * blockDim.x + threadIdx.x;
    int node = t >> 4;
    int li   = (t & 15) << 2;
    if (node >= N_NODES) return;
    float4 acc = *(const float4*)(xws + (size_t)node * 64 + li);   // self term
    int e0 = rowptr[node], e1 = rowptr[node + 1];
    int e = e0;
    for (; e + 4 <= e1; e += 4) {
        int s0 = csr[e + 0], s1 = csr[e + 1], s2 = csr[e + 2], s3 = csr[e + 3];
        float4 v0 = *(const float4*)(xws + (size_t)s0 * 64 + li);
        float4 v1 = *(const float4*)(xws + (size_t)s1 * 64 + li);
        float4 v2 = *(const float4*)(xws + (size_t)s2 * 64 + li);
        float4 v3 = *(const float4*)(xws + (size_t)s3 * 64 + li);
        acc.x += (v0.x + v1.x) + (v2.x + v3.x);
        acc.y += (v0.y + v1.y) + (v2.y + v3.y);
        acc.z += (v0.z + v1.z) + (v2.z + v3.z);
        acc.w += (v0.w + v1.w) + (v2.w + v3.w);
    }
    for (; e < e1; ++e) {
        int s = csr[e];
        float4 v = *(const float4*)(xws + (size_t)s * 64 + li);
        acc.x += v.x; acc.y += v.y; acc.z += v.z; acc.w += v.w;
    }
    float dv = dinv[node];
    float4 bb = *(const float4*)(bias + li);
    float4 r;
    r.x = fmaf(dv, acc.x, bb.x);
    r.y = fmaf(dv, acc.y, bb.y);
    r.z = fmaf(dv, acc.z, bb.z);
    r.w = fmaf(dv, acc.w, bb.w);
    *(float4*)(out + (size_t)node * 64 + li) = r;
}

// ---------------------------------------------------------------------------
// GEMM2 fused: XW2[i,:] = dinv[i] * (relu(H1[i,:]) @ W2[0:64,:] + RB[batch[i],:])
__global__ __launch_bounds__(256) void k_gemm2(const float* __restrict__ H1,
                                               const float* __restrict__ W2,
                                               const float* __restrict__ RB,
                                               const int* __restrict__ batch,
                                               const float* __restrict__ dinv,
                                               float* __restrict__ XW2) {
    __shared__ __align__(16) float As[16][64];   // relu(H1) [k][row]
    __shared__ __align__(16) float Ws[16][64];   // W2a [k][col]
    const int tid  = threadIdx.x;
    const int row0 = blockIdx.x * 64;
    const int c0 = (tid & 15) * 4;   // 0..60
    const int r0 = (tid >> 4) * 4;   // 0..60
    float acc[4][4];
#pragma unroll
    for (int i = 0; i < 4; ++i)
#pragma unroll
        for (int j = 0; j < 4; ++j) acc[i][j] = 0.f;

    const int ar = tid >> 2;             // 0..63
    const int ak = (tid & 3) << 2;       // 0,4,8,12
    const int wk = tid >> 4;             // 0..15
    const int wc = (tid & 15) << 2;      // 0..60

    for (int k0 = 0; k0 < FH; k0 += 16) {
        float4 av = *(const float4*)(H1 + (size_t)(row0 + ar) * 64 + k0 + ak);
        As[ak + 0][ar] = fmaxf(av.x, 0.f);
        As[ak + 1][ar] = fmaxf(av.y, 0.f);
        As[ak + 2][ar] = fmaxf(av.z, 0.f);
        As[ak + 3][ar] = fmaxf(av.w, 0.f);
        *(float4*)&Ws[wk][wc] = *(const float4*)(W2 + (size_t)(k0 + wk) * 64 + wc);
        __syncthreads();
#pragma unroll
        for (int kk = 0; kk < 16; ++kk) {
            float4 w = *(float4*)&Ws[kk][c0];
            float4 a = *(float4*)&As[kk][r0];
            acc[0][0] = fmaf(a.x, w.x, acc[0][0]); acc[0][1] = fmaf(a.x, w.y, acc[0][1]);
            acc[0][2] = fmaf(a.x, w.z, acc[0][2]); acc[0][3] = fmaf(a.x, w.w, acc[0][3]);
            acc[1][0] = fmaf(a.y, w.x, acc[1][0]); acc[1][1] = fmaf(a.y, w.y, acc[1][1]);
            acc[1][2] = fmaf(a.y, w.z, acc[1][2]); acc[1][3] = fmaf(a.y, w.w, acc[1][3]);
            acc[2][0] = fmaf(a.z, w.x, acc[2][0]); acc[2][1] = fmaf(a.z, w.y, acc[2][1]);
            acc[2][2] = fmaf(a.z, w.z, acc[2][2]); acc[2][3] = fmaf(a.z, w.w, acc[2][3]);
            acc[3][0] = fmaf(a.w, w.x, acc[3][0]); acc[3][1] = fmaf(a.w, w.y, acc[3][1]);
            acc[3][2] = fmaf(a.w, w.z, acc[3][2]); acc[3][3] = fmaf(a.w, w.w, acc[3][3]);
        }
        __syncthreads();
    }
#pragma unroll
    for (int i = 0; i < 4; ++i) {
        int row = row0 + r0 + i;
        int bg  = batch[row];
        float dv = dinv[row];
        float4 rb = *(const float4*)(RB + (size_t)bg * 64 + c0);
        float4 xw2;
        xw2.x = (acc[i][0] + rb.x) * dv; xw2.y = (acc[i][1] + rb.y) * dv;
        xw2.z = (acc[i][2] + rb.z) * dv; xw2.w = (acc[i][3] + rb.w) * dv;
        *(float4*)(XW2 + (size_t)row * 64 + c0) = xw2;
    }
}

// ---------------------------------------------------------------------------
__device__ __forceinline__ int lb_search(const int* __restrict__ a, int n, int v) {
    int lo = 0, hi = n;
    while (lo < hi) {
        int m = (lo + hi) >> 1;
        if (a[m] < v) lo = m + 1; else hi = m;
    }
    return lo;
}

// Pool per graph: pooled[b][0:64]  = mean over graph nodes of relu(H2)
//                 pooled[b][64:128]= cnt>0 ? H1[rootindex[b]] : 0
__global__ __launch_bounds__(512) void k_pool(const float* __restrict__ H2,
                                              const float* __restrict__ H1,
                                              const int* __restrict__ batch,
                                              const int* __restrict__ rootindex,
                                              float* __restrict__ pooled) {
    int b    = blockIdx.x;
    int lane = threadIdx.x & 63;
    int wv   = threadIdx.x >> 6;      // 0..7
    int start = lb_search(batch, N_NODES, b);
    int end   = lb_search(batch, N_NODES, b + 1);
    float acc = 0.f;
    for (int i = start + wv; i < end; i += 8)
        acc += fmaxf(H2[(size_t)i * 64 + lane], 0.f);
    __shared__ float red[8][64];
    red[wv][lane] = acc;
    __syncthreads();
    if (wv == 0) {
        float s = 0.f;
#pragma unroll
        for (int w = 0; w < 8; ++w) s += red[w][lane];
        int cnt = end - start;
        float inv = 1.0f / fmaxf((float)cnt, 1.0f);
        pooled[b * 128 + lane] = s * inv;
        float rootv = (cnt > 0) ? H1[(size_t)rootindex[b] * 64 + lane] : 0.f;
        pooled[b * 128 + 64 + lane] = rootv;
    }
}

// ---------------------------------------------------------------------------
// Final FC + log_softmax.  feat = [pooled_bu | pooled_td]  (bu FIRST)
__global__ __launch_bounds__(128) void k_final(const float* __restrict__ ptd,
                                               const float* __restrict__ pbu,
                                               const float* __restrict__ fcW,
                                               const float* __restrict__ fcb,
                                               float* __restrict__ out) {
    int b = threadIdx.x;
    if (b >= NB) return;
    float l[4] = {fcb[0], fcb[1], fcb[2], fcb[3]};
    for (int j = 0; j < 256; ++j) {
        float f = (j < 128) ? pbu[b * 128 + j] : ptd[b * 128 + (j - 128)];
#pragma unroll
        for (int c = 0; c < 4; ++c) l[c] = fmaf(f, fcW[j * 4 + c], l[c]);
    }
    float m = fmaxf(fmaxf(l[0], l[1]), fmaxf(l[2], l[3]));
    float s = expf(l[0] - m) + expf(l[1] - m) + expf(l[2] - m) + expf(l[3] - m);
    float ls = logf(s);
#pragma unroll
    for (int c = 0; c < 4; ++c) out[b * 4 + c] = l[c] - m - ls;
}

// ---------------------------------------------------------------------------
extern "C" void kernel_launch(void* const* d_in, const int* in_sizes, int n_in,
                              void* d_out, int out_size, void* d_ws, size_t ws_size,
                              hipStream_t stream) {
    const float* x     = (const float*)d_in[0];
    const int*   ei    = (const int*)d_in[1];    // [2,E]: src, dst
    const int*   bei   = (const int*)d_in[2];
    const int*   batch = (const int*)d_in[3];
    const int*   rooti = (const int*)d_in[4];
    const float* root  = (const float*)d_in[5];
    const float* W1td  = (const float*)d_in[6];
    const float* b1td  = (const float*)d_in[7];
    const float* W2td  = (const float*)d_in[8];
    const float* b2td  = (const float*)d_in[9];
    const float* W1bu  = (const float*)d_in[10];
    const float* b1bu  = (const float*)d_in[11];
    const float* W2bu  = (const float*)d_in[12];
    const float* b2bu  = (const float*)d_in[13];
    const float* fcW   = (const float*)d_in[14];
    const float* fcb   = (const float*)d_in[15];
    float* out = (float*)d_out;

    char* ws = (char*)d_ws;
    size_t o = 0;
    const size_t NF = (size_t)N_NODES * 64;
    auto alloc_f = [&](size_t n) { float* p = (float*)(ws + o); o += n * 4; return p; };
    auto alloc_i = [&](size_t n) { int*   p = (int*)  (ws + o); o += n * 4; return p; };

    float* XWtd   = alloc_f(NF);
    float* XWbu   = alloc_f(NF);
    float* H1     = alloc_f(NF);
    float* H2     = alloc_f(NF);
    float* dinvtd = alloc_f(N_NODES);
    float* dinvbu = alloc_f(N_NODES);
    float* RBtd   = alloc_f((size_t)NB * 64);
    float* RBbu   = alloc_f((size_t)NB * 64);
    float* pooltd = alloc_f((size_t)NB * 128);
    float* poolbu = alloc_f((size_t)NB * 128);
    int* degi     = alloc_i(2 * (size_t)N_NODES);    // td | bu
    int* rp_td    = alloc_i(N_NODES + 1);
    int* rp_bu    = alloc_i(N_NODES + 1);
    int* cur_td   = alloc_i(N_NODES);
    int* cur_bu   = alloc_i(N_NODES);
    int* bsum     = alloc_i(256);
    int* boff     = alloc_i(256);
    int* csr_td   = alloc_i(N_EDGES);
    int* csr_bu   = alloc_i(N_EDGES);

    const int eb = (N_EDGES + 255) / 256;            // 12500

    // degrees + dinv
    hipMemsetAsync(degi, 0, 2 * (size_t)N_NODES * sizeof(int), stream);
    k_degi<<<eb, 256, 0, stream>>>(ei + N_EDGES, bei + N_EDGES, degi);
    k_dinv<<<(2 * N_NODES + 255) / 256, 256, 0, stream>>>(degi, dinvtd);

    // CSR build (td then bu; scan scratch reused — stream-ordered)
    k_scanA<<<NBLK, 256, 0, stream>>>(degi, bsum);
    k_scanB<<<1, 256, 0, stream>>>(bsum, boff);
    k_scanC<<<NBLK, 256, 0, stream>>>(degi, boff, rp_td, cur_td);
    k_fill<<<eb, 256, 0, stream>>>(ei, ei + N_EDGES, cur_td, csr_td);

    k_scanA<<<NBLK, 256, 0, stream>>>(degi + N_NODES, bsum);
    k_scanB<<<1, 256, 0, stream>>>(bsum, boff);
    k_scanC<<<NBLK, 256, 0, stream>>>(degi + N_NODES, boff, rp_bu, cur_bu);
    k_fill<<<eb, 256, 0, stream>>>(bei, bei + N_EDGES, cur_bu, csr_bu);

    // big fused matmul + dinv prescale + root-projection
    k_gemm1<<<(N_NODES + 127) / 128, 256, 0, stream>>>(x, W1td, W1bu, dinvtd, dinvbu,
                                                       XWtd, XWbu);
    k_rb<<<NB, 128, 0, stream>>>(root, W2td, W2bu, RBtd, RBbu);

    const int gb = (N_NODES * 16) / 256;             // 12500

    // ---- td branch ----
    k_gather<<<gb, 256, 0, stream>>>(rp_td, csr_td, dinvtd, XWtd, b1td, H1);
    k_gemm2<<<N_NODES / 64, 256, 0, stream>>>(H1, W2td, RBtd, batch, dinvtd, XWtd /*XW2*/);
    k_gather<<<gb, 256, 0, stream>>>(rp_td, csr_td, dinvtd, XWtd, b2td, H2);
    k_pool<<<NB, 512, 0, stream>>>(H2, H1, batch, rooti, pooltd);

    // ---- bu branch ----
    k_gather<<<gb, 256, 0, stream>>>(rp_bu, csr_bu, dinvbu, XWbu, b1bu, H1);
    k_gemm2<<<N_NODES / 64, 256, 0, stream>>>(H1, W2bu, RBbu, batch, dinvbu, XWbu /*XW2*/);
    k_gather<<<gb, 256, 0, stream>>>(rp_bu, csr_bu, dinvbu, XWbu, b2bu, H2);
    k_pool<<<NB, 512, 0, stream>>>(H2, H1, batch, rooti, poolbu);

    // ---- head ----
    k_final<<<1, 128, 0, stream>>>(pooltd, poolbu, fcW, fcb, out);
}

// Round 3
// 2723.704 us; speedup vs baseline: 1.0106x; 1.0016x over previous
//
#include <hip/hip_runtime.h>
#include <math.h>

#define N_NODES 200000
#define N_EDGES 3200000
#define NB      128
#define FIN     768
#define FH      64      // HID == OUT == 64
#define NC      4

#define SCAN_TILE 1024                      // 256 threads x 4 elems
#define NBLK ((N_NODES + SCAN_TILE - 1) / SCAN_TILE)   // 196 (<=256 required)

// ---------------------------------------------------------------------------
// Integer in-degree of dst for both edge sets. degi[0..N)=td, [N..2N)=bu.
__global__ __launch_bounds__(256) void k_degi(const int* __restrict__ dst_td,
                                              const int* __restrict__ dst_bu,
                                              int* __restrict__ degi) {
    int i = blockIdx.x * blockDim.x + threadIdx.x;
    if (i < N_EDGES) {
        atomicAdd(degi + dst_td[i], 1);
        atomicAdd(degi + N_NODES + dst_bu[i], 1);
    }
}

// dinv = rsqrt(deg + 1)   (self-loop included; always > 0)
__global__ __launch_bounds__(256) void k_dinv(const int* __restrict__ degi,
                                              float* __restrict__ dv) {
    int i = blockIdx.x * blockDim.x + threadIdx.x;
    if (i < 2 * N_NODES) dv[i] = rsqrtf((float)degi[i] + 1.0f);
}

// ---------------------------------------------------------------------------
// Prefix-scan of degrees -> rowptr (exclusive), cursor (copy of rowptr).
__global__ __launch_bounds__(256) void k_scanA(const int* __restrict__ deg,
                                               int* __restrict__ bsum) {
    __shared__ int sh[256];
    int t = threadIdx.x, b = blockIdx.x;
    int base = b * SCAN_TILE + t * 4;
    int s = 0;
#pragma unroll
    for (int j = 0; j < 4; ++j) {
        int idx = base + j;
        if (idx < N_NODES) s += deg[idx];
    }
    sh[t] = s;
    __syncthreads();
    for (int off = 128; off > 0; off >>= 1) {
        if (t < off) sh[t] += sh[t + off];
        __syncthreads();
    }
    if (t == 0) bsum[b] = sh[0];
}

__global__ __launch_bounds__(256) void k_scanB(const int* __restrict__ bsum,
                                               int* __restrict__ boff) {
    __shared__ int sh[256];
    int t = threadIdx.x;
    int v = (t < NBLK) ? bsum[t] : 0;
    sh[t] = v;
    __syncthreads();
    for (int off = 1; off < 256; off <<= 1) {
        int a = (t >= off) ? sh[t - off] : 0;
        __syncthreads();
        sh[t] += a;
        __syncthreads();
    }
    if (t < NBLK) boff[t] = sh[t] - v;   // exclusive
}

__global__ __launch_bounds__(256) void k_scanC(const int* __restrict__ deg,
                                               const int* __restrict__ boff,
                                               int* __restrict__ rowptr,
                                               int* __restrict__ cursor) {
    __shared__ int sh[256];
    int t = threadIdx.x, b = blockIdx.x;
    int base = b * SCAN_TILE + t * 4;
    int v[4];
    int tot = 0;
#pragma unroll
    for (int j = 0; j < 4; ++j) {
        int idx = base + j;
        v[j] = (idx < N_NODES) ? deg[idx] : 0;
        tot += v[j];
    }
    sh[t] = tot;
    __syncthreads();
    for (int off = 1; off < 256; off <<= 1) {
        int a = (t >= off) ? sh[t - off] : 0;
        __syncthreads();
        sh[t] += a;
        __syncthreads();
    }
    int run = boff[b] + sh[t] - tot;     // global exclusive prefix at base
#pragma unroll
    for (int j = 0; j < 4; ++j) {
        int idx = base + j;
        if (idx < N_NODES) {
            rowptr[idx] = run;
            cursor[idx] = run;
            run += v[j];
        }
    }
    if (b == 0 && t == 0) rowptr[N_NODES] = N_EDGES;
}

// Counting-sort edges into CSR by dst (order within a row is arbitrary).
__global__ __launch_bounds__(256) void k_fill(const int* __restrict__ src,
                                              const int* __restrict__ dst,
                                              int* __restrict__ cursor,
                                              int* __restrict__ csr) {
    int e = blockIdx.x * blockDim.x + threadIdx.x;
    if (e < N_EDGES) {
        int d = dst[e];
        int pos = atomicAdd(cursor + d, 1);
        csr[pos] = src[e];
    }
}

// ---------------------------------------------------------------------------
// GEMM1: XWtd = dinvtd[i] * (x @ W1_td),  XWbu = dinvbu[i] * (x @ W1_bu)
// 128x128 tile, 256 threads, 8x8 per thread.  BK=16 -> 16 KB LDS total so
// 4 blocks/CU fit under the ~64 KB effective LDS occupancy pool (round-2
// post-mortem: 32 KB -> 2 blocks/CU -> VALUBusy 59%).  XOR swizzle
// row^=(kquad<<3) kills the transpose-write bank conflicts.
#define FMA4(A, s, W) \
    A.x = fmaf(s, W.x, A.x); A.y = fmaf(s, W.y, A.y); \
    A.z = fmaf(s, W.z, A.z); A.w = fmaf(s, W.w, A.w)

__global__ __launch_bounds__(256) void k_gemm1(const float* __restrict__ x,
                                               const float* __restrict__ Wtd,
                                               const float* __restrict__ Wbu,
                                               const float* __restrict__ dinvtd,
                                               const float* __restrict__ dinvbu,
                                               float* __restrict__ XWtd,
                                               float* __restrict__ XWbu) {
    __shared__ __align__(16) float As[16][128];   // [k][row] swizzled (8 KB)
    __shared__ __align__(16) float Ws[16][128];   // [k][col] td|bu   (8 KB)
    const int tid  = threadIdx.x;
    const int row0 = blockIdx.x * 128;
    const int tx = tid & 15, ty = tid >> 4;
    const int c0 = tx * 4;               // col quad (0..60)
    const int r0 = ty * 4;               // row quad (0..60)
    const int a_kc  = tid & 3;           // k float4-chunk 0..3
    const int a_row = tid >> 2;          // 0..63 (+64p)
    const int w_cc  = tid & 31;          // col chunk 0..31
    const int w_k   = tid >> 5;          // 0..7 (+8p)
    const int a_sw  = a_kc << 3;         // write swizzle (bits 3-4)

    float4 acc[2][4][2];
#pragma unroll
    for (int a = 0; a < 2; ++a)
#pragma unroll
        for (int b = 0; b < 4; ++b)
#pragma unroll
            for (int c = 0; c < 2; ++c) acc[a][b][c] = make_float4(0.f, 0.f, 0.f, 0.f);

    for (int k0 = 0; k0 < FIN; k0 += 16) {
        float4 xv[2], wv[2];
#pragma unroll
        for (int p = 0; p < 2; ++p) {
            int grow = row0 + a_row + 64 * p;
            if (grow > N_NODES - 1) grow = N_NODES - 1;     // clamp tail (stores guarded)
            xv[p] = *(const float4*)(x + (size_t)grow * FIN + k0 + a_kc * 4);
        }
#pragma unroll
        for (int p = 0; p < 2; ++p) {
            int kw = w_k + 8 * p;
            const float* Wp = (w_cc < 16) ? (Wtd + (size_t)(k0 + kw) * 64 + w_cc * 4)
                                          : (Wbu + (size_t)(k0 + kw) * 64 + w_cc * 4 - 64);
            wv[p] = *(const float4*)Wp;
        }
        __syncthreads();                 // previous tile fully consumed
        {
            int sr = a_row ^ a_sw;
#pragma unroll
            for (int p = 0; p < 2; ++p) {
                int srow = sr + 64 * p;                     // +64p doesn't touch bits 3-4
                As[a_kc * 4 + 0][srow] = xv[p].x;
                As[a_kc * 4 + 1][srow] = xv[p].y;
                As[a_kc * 4 + 2][srow] = xv[p].z;
                As[a_kc * 4 + 3][srow] = xv[p].w;
            }
#pragma unroll
            for (int p = 0; p < 2; ++p)
                *(float4*)&Ws[w_k + 8 * p][w_cc * 4] = wv[p];
        }
        __syncthreads();

#pragma unroll
        for (int kk = 0; kk < 16; ++kk) {
            int sw = (kk >> 2) << 3;
            int ra = r0 ^ sw;
            float4 a0 = *(const float4*)&As[kk][ra];
            float4 a1 = *(const float4*)&As[kk][ra + 64];
            float4 w0 = *(const float4*)&Ws[kk][c0];
            float4 w1 = *(const float4*)&Ws[kk][c0 + 64];
            FMA4(acc[0][0][0], a0.x, w0); FMA4(acc[0][0][1], a0.x, w1);
            FMA4(acc[0][1][0], a0.y, w0); FMA4(acc[0][1][1], a0.y, w1);
            FMA4(acc[0][2][0], a0.z, w0); FMA4(acc[0][2][1], a0.z, w1);
            FMA4(acc[0][3][0], a0.w, w0); FMA4(acc[0][3][1], a0.w, w1);
            FMA4(acc[1][0][0], a1.x, w0); FMA4(acc[1][0][1], a1.x, w1);
            FMA4(acc[1][1][0], a1.y, w0); FMA4(acc[1][1][1], a1.y, w1);
            FMA4(acc[1][2][0], a1.z, w0); FMA4(acc[1][2][1], a1.z, w1);
            FMA4(acc[1][3][0], a1.w, w0); FMA4(acc[1][3][1], a1.w, w1);
        }
        __syncthreads();
    }
#pragma unroll
    for (int rh = 0; rh < 2; ++rh)
#pragma unroll
        for (int i = 0; i < 4; ++i) {
            int rr = row0 + rh * 64 + r0 + i;
            if (rr < N_NODES) {
                float dtd = dinvtd[rr], dbu = dinvbu[rr];
                float4 v0 = acc[rh][i][0];
                float4 v1 = acc[rh][i][1];
                float4 o0 = make_float4(v0.x * dtd, v0.y * dtd, v0.z * dtd, v0.w * dtd);
                float4 o1 = make_float4(v1.x * dbu, v1.y * dbu, v1.z * dbu, v1.w * dbu);
                *(float4*)(XWtd + (size_t)rr * 64 + c0) = o0;
                *(float4*)(XWbu + (size_t)rr * 64 + c0) = o1;
            }
        }
}

// ---------------------------------------------------------------------------
// RB[b][c] = sum_k relu(root[b,k]) * W2[(64+k), c]  for both branches
__global__ __launch_bounds__(128) void k_rb(const float* __restrict__ root,
                                            const float* __restrict__ W2td,
                                            const float* __restrict__ W2bu,
                                            float* __restrict__ RBtd,
                                            float* __restrict__ RBbu) {
    int b = blockIdx.x;
    int c = threadIdx.x;                 // 0..127
    const float* W2 = (c < 64) ? W2td : W2bu;
    int cc = c & 63;
    const float* rp = root + (size_t)b * FIN;
    float s = 0.f;
    for (int k = 0; k < FIN; ++k) {
        float r = fmaxf(rp[k], 0.f);
        s = fmaf(r, W2[(size_t)(64 + k) * 64 + cc], s);
    }
    (c < 64 ? RBtd : RBbu)[b * 64 + cc] = s;
}

// ---------------------------------------------------------------------------
// CSR gather over PRE-SCALED inputs (xws[i] = dinv[i] * xw[i]):
//   out[i] = bias + dinv[i] * (xws[i] + sum_e xws[src])
// quarter-wave (16 lanes x float4) per node; edge loop unrolled x8 with dual
// accumulators for memory-level parallelism.
__global__ __launch_bounds__(256) void k_gather(const int* __restrict__ rowptr,
                                                const int* __restrict__ csr,
                                                const float* __restrict__ dinv,
                                                const float* __restrict__ xws,
                                                const float* __restrict__ bias,
                                                float* __restrict__ out) {
    int t    = blockIdx.x * blockDim.x + threadIdx.x;
    int node = t >> 4;
    int li   = (t & 15) << 2;
    if (node >= N_NODES) return;
    float4 acc0 = *(const float4*)(xws + (size_t)node * 64 + li);  // self term
    float4 acc1 = make_float4(0.f, 0.f, 0.f, 0.f);
    int e0 = rowptr[node], e1 = rowptr[node + 1];
    int e = e0;
    for (; e + 8 <= e1; e += 8) {
        int s0 = csr[e + 0], s1 = csr[e + 1], s2 = csr[e + 2], s3 = csr[e + 3];
        int s4 = csr[e + 4], s5 = csr[e + 5], s6 = csr[e + 6], s7 = csr[e + 7];
        float4 v0 = *(const float4*)(xws + (size_t)s0 * 64 + li);
        float4 v1 = *(const float4*)(xws + (size_t)s1 * 64 + li);
        float4 v2 = *(const float4*)(xws + (size_t)s2 * 64 + li);
        float4 v3 = *(const float4*)(xws + (size_t)s3 * 64 + li);
        float4 v4 = *(const float4*)(xws + (size_t)s4 * 64 + li);
        float4 v5 = *(const float4*)(xws + (size_t)s5 * 64 + li);
        float4 v6 = *(const float4*)(xws + (size_t)s6 * 64 + li);
        float4 v7 = *(const float4*)(xws + (size_t)s7 * 64 + li);
        acc0.x += (v0.x + v1.x) + (v2.x + v3.x);
        acc0.y += (v0.y + v1.y) + (v2.y + v3.y);
        acc0.z += (v0.z + v1.z) + (v2.z + v3.z);
        acc0.w += (v0.w + v1.w) + (v2.w + v3.w);
        acc1.x += (v4.x + v5.x) + (v6.x + v7.x);
        acc1.y += (v4.y + v5.y) + (v6.y + v7.y);
        acc1.z += (v4.z + v5.z) + (v6.z + v7.z);
        acc1.w += (v4.w + v5.w) + (v6.w + v7.w);
    }
    for (; e + 4 <= e1; e += 4) {
        int s0 = csr[e + 0], s1 = csr[e + 1], s2 = csr[e + 2], s3 = csr[e + 3];
        float4 v0 = *(const float4*)(xws + (size_t)s0 * 64 + li);
        float4 v1 = *(const float4*)(xws + (size_t)s1 * 64 + li);
        float4 v2 = *(const float4*)(xws + (size_t)s2 * 64 + li);
        float4 v3 = *(const float4*)(xws + (size_t)s3 * 64 + li);
        acc1.x += (v0.x + v1.x) + (v2.x + v3.x);
        acc1.y += (v0.y + v1.y) + (v2.y + v3.y);
        acc1.z += (v0.z + v1.z) + (v2.z + v3.z);
        acc1.w += (v0.w + v1.w) + (v2.w + v3.w);
    }
    for (; e < e1; ++e) {
        int s = csr[e];
        float4 v = *(const float4*)(xws + (size_t)s * 64 + li);
        acc0.x += v.x; acc0.y += v.y; acc0.z += v.z; acc0.w += v.w;
    }
    acc0.x += acc1.x; acc0.y += acc1.y; acc0.z += acc1.z; acc0.w += acc1.w;
    float dv = dinv[node];
    float4 bb = *(const float4*)(bias + li);
    float4 r;
    r.x = fmaf(dv, acc0.x, bb.x);
    r.y = fmaf(dv, acc0.y, bb.y);
    r.z = fmaf(dv, acc0.z, bb.z);
    r.w = fmaf(dv, acc0.w, bb.w);
    *(float4*)(out + (size_t)node * 64 + li) = r;
}

// ---------------------------------------------------------------------------
// GEMM2 fused: XW2[i,:] = dinv[i] * (relu(H1[i,:]) @ W2[0:64,:] + RB[batch[i],:])
__global__ __launch_bounds__(256) void k_gemm2(const float* __restrict__ H1,
                                               const float* __restrict__ W2,
                                               const float* __restrict__ RB,
                                               const int* __restrict__ batch,
                                               const float* __restrict__ dinv,
                                               float* __restrict__ XW2) {
    __shared__ __align__(16) float As[16][64];   // relu(H1) [k][row]
    __shared__ __align__(16) float Ws[16][64];   // W2a [k][col]
    const int tid  = threadIdx.x;
    const int row0 = blockIdx.x * 64;
    const int c0 = (tid & 15) * 4;   // 0..60
    const int r0 = (tid >> 4) * 4;   // 0..60
    float acc[4][4];
#pragma unroll
    for (int i = 0; i < 4; ++i)
#pragma unroll
        for (int j = 0; j < 4; ++j) acc[i][j] = 0.f;

    const int ar = tid >> 2;             // 0..63
    const int ak = (tid & 3) << 2;       // 0,4,8,12
    const int wk = tid >> 4;             // 0..15
    const int wc = (tid & 15) << 2;      // 0..60

    for (int k0 = 0; k0 < FH; k0 += 16) {
        float4 av = *(const float4*)(H1 + (size_t)(row0 + ar) * 64 + k0 + ak);
        As[ak + 0][ar] = fmaxf(av.x, 0.f);
        As[ak + 1][ar] = fmaxf(av.y, 0.f);
        As[ak + 2][ar] = fmaxf(av.z, 0.f);
        As[ak + 3][ar] = fmaxf(av.w, 0.f);
        *(float4*)&Ws[wk][wc] = *(const float4*)(W2 + (size_t)(k0 + wk) * 64 + wc);
        __syncthreads();
#pragma unroll
        for (int kk = 0; kk < 16; ++kk) {
            float4 w = *(float4*)&Ws[kk][c0];
            float4 a = *(float4*)&As[kk][r0];
            acc[0][0] = fmaf(a.x, w.x, acc[0][0]); acc[0][1] = fmaf(a.x, w.y, acc[0][1]);
            acc[0][2] = fmaf(a.x, w.z, acc[0][2]); acc[0][3] = fmaf(a.x, w.w, acc[0][3]);
            acc[1][0] = fmaf(a.y, w.x, acc[1][0]); acc[1][1] = fmaf(a.y, w.y, acc[1][1]);
            acc[1][2] = fmaf(a.y, w.z, acc[1][2]); acc[1][3] = fmaf(a.y, w.w, acc[1][3]);
            acc[2][0] = fmaf(a.z, w.x, acc[2][0]); acc[2][1] = fmaf(a.z, w.y, acc[2][1]);
            acc[2][2] = fmaf(a.z, w.z, acc[2][2]); acc[2][3] = fmaf(a.z, w.w, acc[2][3]);
            acc[3][0] = fmaf(a.w, w.x, acc[3][0]); acc[3][1] = fmaf(a.w, w.y, acc[3][1]);
            acc[3][2] = fmaf(a.w, w.z, acc[3][2]); acc[3][3] = fmaf(a.w, w.w, acc[3][3]);
        }
        __syncthreads();
    }
#pragma unroll
    for (int i = 0; i < 4; ++i) {
        int row = row0 + r0 + i;
        int bg  = batch[row];
        float dv = dinv[row];
        float4 rb = *(const float4*)(RB + (size_t)bg * 64 + c0);
        float4 xw2;
        xw2.x = (acc[i][0] + rb.x) * dv; xw2.y = (acc[i][1] + rb.y) * dv;
        xw2.z = (acc[i][2] + rb.z) * dv; xw2.w = (acc[i][3] + rb.w) * dv;
        *(float4*)(XW2 + (size_t)row * 64 + c0) = xw2;
    }
}

// ---------------------------------------------------------------------------
__device__ __forceinline__ int lb_search(const int* __restrict__ a, int n, int v) {
    int lo = 0, hi = n;
    while (lo < hi) {
        int m = (lo + hi) >> 1;
        if (a[m] < v) lo = m + 1; else hi = m;
    }
    return lo;
}

// Pool per graph: pooled[b][0:64]  = mean over graph nodes of relu(H2)
//                 pooled[b][64:128]= cnt>0 ? H1[rootindex[b]] : 0
__global__ __launch_bounds__(512) void k_pool(const float* __restrict__ H2,
                                              const float* __restrict__ H1,
                                              const int* __restrict__ batch,
                                              const int* __restrict__ rootindex,
                                              float* __restrict__ pooled) {
    int b    = blockIdx.x;
    int lane = threadIdx.x & 63;
    int wv   = threadIdx.x >> 6;      // 0..7
    int start = lb_search(batch, N_NODES, b);
    int end   = lb_search(batch, N_NODES, b + 1);
    float acc = 0.f;
    for (int i = start + wv; i < end; i += 8)
        acc += fmaxf(H2[(size_t)i * 64 + lane], 0.f);
    __shared__ float red[8][64];
    red[wv][lane] = acc;
    __syncthreads();
    if (wv == 0) {
        float s = 0.f;
#pragma unroll
        for (int w = 0; w < 8; ++w) s += red[w][lane];
        int cnt = end - start;
        float inv = 1.0f / fmaxf((float)cnt, 1.0f);
        pooled[b * 128 + lane] = s * inv;
        float rootv = (cnt > 0) ? H1[(size_t)rootindex[b] * 64 + lane] : 0.f;
        pooled[b * 128 + 64 + lane] = rootv;
    }
}

// ---------------------------------------------------------------------------
// Final FC + log_softmax.  feat = [pooled_bu | pooled_td]  (bu FIRST)
__global__ __launch_bounds__(128) void k_final(const float* __restrict__ ptd,
                                               const float* __restrict__ pbu,
                                               const float* __restrict__ fcW,
                                               const float* __restrict__ fcb,
                                               float* __restrict__ out) {
    int b = threadIdx.x;
    if (b >= NB) return;
    float l[4] = {fcb[0], fcb[1], fcb[2], fcb[3]};
    for (int j = 0; j < 256; ++j) {
        float f = (j < 128) ? pbu[b * 128 + j] : ptd[b * 128 + (j - 128)];
#pragma unroll
        for (int c = 0; c < 4; ++c) l[c] = fmaf(f, fcW[j * 4 + c], l[c]);
    }
    float m = fmaxf(fmaxf(l[0], l[1]), fmaxf(l[2], l[3]));
    float s = expf(l[0] - m) + expf(l[1] - m) + expf(l[2] - m) + expf(l[3] - m);
    float ls = logf(s);
#pragma unroll
    for (int c = 0; c < 4; ++c) out[b * 4 + c] = l[c] - m - ls;
}

// ---------------------------------------------------------------------------
extern "C" void kernel_launch(void* const* d_in, const int* in_sizes, int n_in,
                              void* d_out, int out_size, void* d_ws, size_t ws_size,
                              hipStream_t stream) {
    const float* x     = (const float*)d_in[0];
    const int*   ei    = (const int*)d_in[1];    // [2,E]: src, dst
    const int*   bei   = (const int*)d_in[2];
    const int*   batch = (const int*)d_in[3];
    const int*   rooti = (const int*)d_in[4];
    const float* root  = (const float*)d_in[5];
    const float* W1td  = (const float*)d_in[6];
    const float* b1td  = (const float*)d_in[7];
    const float* W2td  = (const float*)d_in[8];
    const float* b2td  = (const float*)d_in[9];
    const float* W1bu  = (const float*)d_in[10];
    const float* b1bu  = (const float*)d_in[11];
    const float* W2bu  = (const float*)d_in[12];
    const float* b2bu  = (const float*)d_in[13];
    const float* fcW   = (const float*)d_in[14];
    const float* fcb   = (const float*)d_in[15];
    float* out = (float*)d_out;

    char* ws = (char*)d_ws;
    size_t o = 0;
    const size_t NF = (size_t)N_NODES * 64;
    auto alloc_f = [&](size_t n) { float* p = (float*)(ws + o); o += n * 4; return p; };
    auto alloc_i = [&](size_t n) { int*   p = (int*)  (ws + o); o += n * 4; return p; };

    float* XWtd   = alloc_f(NF);
    float* XWbu   = alloc_f(NF);
    float* H1     = alloc_f(NF);
    float* H2     = alloc_f(NF);
    float* dinvtd = alloc_f(N_NODES);
    float* dinvbu = alloc_f(N_NODES);
    float* RBtd   = alloc_f((size_t)NB * 64);
    float* RBbu   = alloc_f((size_t)NB * 64);
    float* pooltd = alloc_f((size_t)NB * 128);
    float* poolbu = alloc_f((size_t)NB * 128);
    int* degi     = alloc_i(2 * (size_t)N_NODES);    // td | bu
    int* rp_td    = alloc_i(N_NODES + 1);
    int* rp_bu    = alloc_i(N_NODES + 1);
    int* cur_td   = alloc_i(N_NODES);
    int* cur_bu   = alloc_i(N_NODES);
    int* bsum     = alloc_i(256);
    int* boff     = alloc_i(256);
    int* csr_td   = alloc_i(N_EDGES);
    int* csr_bu   = alloc_i(N_EDGES);

    const int eb = (N_EDGES + 255) / 256;            // 12500

    // degrees + dinv
    hipMemsetAsync(degi, 0, 2 * (size_t)N_NODES * sizeof(int), stream);
    k_degi<<<eb, 256, 0, stream>>>(ei + N_EDGES, bei + N_EDGES, degi);
    k_dinv<<<(2 * N_NODES + 255) / 256, 256, 0, stream>>>(degi, dinvtd);

    // CSR build (td then bu; scan scratch reused — stream-ordered)
    k_scanA<<<NBLK, 256, 0, stream>>>(degi, bsum);
    k_scanB<<<1, 256, 0, stream>>>(bsum, boff);
    k_scanC<<<NBLK, 256, 0, stream>>>(degi, boff, rp_td, cur_td);
    k_fill<<<eb, 256, 0, stream>>>(ei, ei + N_EDGES, cur_td, csr_td);

    k_scanA<<<NBLK, 256, 0, stream>>>(degi + N_NODES, bsum);
    k_scanB<<<1, 256, 0, stream>>>(bsum, boff);
    k_scanC<<<NBLK, 256, 0, stream>>>(degi + N_NODES, boff, rp_bu, cur_bu);
    k_fill<<<eb, 256, 0, stream>>>(bei, bei + N_EDGES, cur_bu, csr_bu);

    // big fused matmul + dinv prescale + root-projection
    k_gemm1<<<(N_NODES + 127) / 128, 256, 0, stream>>>(x, W1td, W1bu, dinvtd, dinvbu,
                                                       XWtd, XWbu);
    k_rb<<<NB, 128, 0, stream>>>(root, W2td, W2bu, RBtd, RBbu);

    const int gb = (N_NODES * 16) / 256;             // 12500

    // ---- td branch ----
    k_gather<<<gb, 256, 0, stream>>>(rp_td, csr_td, dinvtd, XWtd, b1td, H1);
    k_gemm2<<<N_NODES / 64, 256, 0, stream>>>(H1, W2td, RBtd, batch, dinvtd, XWtd /*XW2*/);
    k_gather<<<gb, 256, 0, stream>>>(rp_td, csr_td, dinvtd, XWtd, b2td, H2);
    k_pool<<<NB, 512, 0, stream>>>(H2, H1, batch, rooti, pooltd);

    // ---- bu branch ----
    k_gather<<<gb, 256, 0, stream>>>(rp_bu, csr_bu, dinvbu, XWbu, b1bu, H1);
    k_gemm2<<<N_NODES / 64, 256, 0, stream>>>(H1, W2bu, RBbu, batch, dinvbu, XWbu /*XW2*/);
    k_gather<<<gb, 256, 0, stream>>>(rp_bu, csr_bu, dinvbu, XWbu, b2bu, H2);
    k_pool<<<NB, 512, 0, stream>>>(H2, H1, batch, rooti, poolbu);

    // ---- head ----
    k_final<<<1, 128, 0, stream>>>(pooltd, poolbu, fcW, fcb, out);
}

// Round 4
// 2502.200 us; speedup vs baseline: 1.1001x; 1.0885x over previous
//
#include <hip/hip_runtime.h>
#include <math.h>

#define N_NODES 200000
#define N_EDGES 3200000
#define NB      128
#define FIN     768
#define FH      64      // HID == OUT == 64
#define NC      4

#define SCAN_TILE 1024                      // 256 threads x 4 elems
#define NBLK ((N_NODES + SCAN_TILE - 1) / SCAN_TILE)   // 196 (<=256 required)

// ---------------------------------------------------------------------------
// bf16 helpers (storage format for gathered arrays; f32 compute throughout)
__device__ __forceinline__ unsigned short f2bf(float f) {
    unsigned int u = __float_as_uint(f);
    u += 0x7fffu + ((u >> 16) & 1u);      // round-to-nearest-even
    return (unsigned short)(u >> 16);
}
__device__ __forceinline__ ushort4 pack4(float4 v) {
    ushort4 h;
    h.x = f2bf(v.x); h.y = f2bf(v.y); h.z = f2bf(v.z); h.w = f2bf(v.w);
    return h;
}
__device__ __forceinline__ float4 unpack4(ushort4 h) {
    float4 f;
    f.x = __uint_as_float((unsigned int)h.x << 16);
    f.y = __uint_as_float((unsigned int)h.y << 16);
    f.z = __uint_as_float((unsigned int)h.z << 16);
    f.w = __uint_as_float((unsigned int)h.w << 16);
    return f;
}

// ---------------------------------------------------------------------------
// Integer in-degree of dst for both edge sets. degi[0..N)=td, [N..2N)=bu.
__global__ __launch_bounds__(256) void k_degi(const int* __restrict__ dst_td,
                                              const int* __restrict__ dst_bu,
                                              int* __restrict__ degi) {
    int i = blockIdx.x * blockDim.x + threadIdx.x;
    if (i < N_EDGES) {
        atomicAdd(degi + dst_td[i], 1);
        atomicAdd(degi + N_NODES + dst_bu[i], 1);
    }
}

// dinv = rsqrt(deg + 1)   (self-loop included; always > 0)
__global__ __launch_bounds__(256) void k_dinv(const int* __restrict__ degi,
                                              float* __restrict__ dv) {
    int i = blockIdx.x * blockDim.x + threadIdx.x;
    if (i < 2 * N_NODES) dv[i] = rsqrtf((float)degi[i] + 1.0f);
}

// ---------------------------------------------------------------------------
// Prefix-scan of degrees -> rowptr (exclusive), cursor (copy of rowptr).
__global__ __launch_bounds__(256) void k_scanA(const int* __restrict__ deg,
                                               int* __restrict__ bsum) {
    __shared__ int sh[256];
    int t = threadIdx.x, b = blockIdx.x;
    int base = b * SCAN_TILE + t * 4;
    int s = 0;
#pragma unroll
    for (int j = 0; j < 4; ++j) {
        int idx = base + j;
        if (idx < N_NODES) s += deg[idx];
    }
    sh[t] = s;
    __syncthreads();
    for (int off = 128; off > 0; off >>= 1) {
        if (t < off) sh[t] += sh[t + off];
        __syncthreads();
    }
    if (t == 0) bsum[b] = sh[0];
}

__global__ __launch_bounds__(256) void k_scanB(const int* __restrict__ bsum,
                                               int* __restrict__ boff) {
    __shared__ int sh[256];
    int t = threadIdx.x;
    int v = (t < NBLK) ? bsum[t] : 0;
    sh[t] = v;
    __syncthreads();
    for (int off = 1; off < 256; off <<= 1) {
        int a = (t >= off) ? sh[t - off] : 0;
        __syncthreads();
        sh[t] += a;
        __syncthreads();
    }
    if (t < NBLK) boff[t] = sh[t] - v;   // exclusive
}

__global__ __launch_bounds__(256) void k_scanC(const int* __restrict__ deg,
                                               const int* __restrict__ boff,
                                               int* __restrict__ rowptr,
                                               int* __restrict__ cursor) {
    __shared__ int sh[256];
    int t = threadIdx.x, b = blockIdx.x;
    int base = b * SCAN_TILE + t * 4;
    int v[4];
    int tot = 0;
#pragma unroll
    for (int j = 0; j < 4; ++j) {
        int idx = base + j;
        v[j] = (idx < N_NODES) ? deg[idx] : 0;
        tot += v[j];
    }
    sh[t] = tot;
    __syncthreads();
    for (int off = 1; off < 256; off <<= 1) {
        int a = (t >= off) ? sh[t - off] : 0;
        __syncthreads();
        sh[t] += a;
        __syncthreads();
    }
    int run = boff[b] + sh[t] - tot;     // global exclusive prefix at base
#pragma unroll
    for (int j = 0; j < 4; ++j) {
        int idx = base + j;
        if (idx < N_NODES) {
            rowptr[idx] = run;
            cursor[idx] = run;
            run += v[j];
        }
    }
    if (b == 0 && t == 0) rowptr[N_NODES] = N_EDGES;
}

// Counting-sort edges into CSR by dst (order within a row is arbitrary).
__global__ __launch_bounds__(256) void k_fill(const int* __restrict__ src,
                                              const int* __restrict__ dst,
                                              int* __restrict__ cursor,
                                              int* __restrict__ csr) {
    int e = blockIdx.x * blockDim.x + threadIdx.x;
    if (e < N_EDGES) {
        int d = dst[e];
        int pos = atomicAdd(cursor + d, 1);
        csr[pos] = src[e];
    }
}

// ---------------------------------------------------------------------------
// GEMM1: XWtd = bf16( dinvtd[i] * (x @ W1_td) ), XWbu likewise.
// 64x128 tile (round-0 high-occupancy layout: ~40 VGPR, 12 KB LDS), 256 thr,
// 8x4 acc/thread, PLUS the round-3-proven XOR swizzle on the As transpose
// write: column ^= (tid&3)<<3 spreads the 4 aliasing lanes across bits 3-4
// (32-column span -> 2 lanes/bank = free). Read side applies the same XOR
// keyed by kk quad. Outputs packed bf16 (halves store traffic; gathers are
// byte-bound).
__global__ __launch_bounds__(256) void k_gemm1(const float* __restrict__ x,
                                               const float* __restrict__ Wtd,
                                               const float* __restrict__ Wbu,
                                               const float* __restrict__ dinvtd,
                                               const float* __restrict__ dinvbu,
                                               unsigned short* __restrict__ XWtd,
                                               unsigned short* __restrict__ XWbu) {
    __shared__ __align__(16) float As[16][64];    // [k][row] swizzled (4 KB)
    __shared__ __align__(16) float Ws[16][128];   // [k][col] td|bu   (8 KB)
    const int tid  = threadIdx.x;
    const int row0 = blockIdx.x * 64;            // grid 3125: exact, no tail
    const int c0 = (tid & 31) * 4;   // 0..124 (cols; >=64 -> bu)
    const int r0 = (tid >> 5) * 8;   // 0..56  (rows)
    const int ar  = tid >> 2;        // 0..63
    const int ak  = (tid & 3) << 2;  // 0,4,8,12
    const int asw = (tid & 3) << 3;  // As write swizzle {0,8,16,24}

    float acc[8][4];
#pragma unroll
    for (int i = 0; i < 8; ++i)
#pragma unroll
        for (int j = 0; j < 4; ++j) acc[i][j] = 0.f;

    for (int k0 = 0; k0 < FIN; k0 += 16) {
        float4 av = *(const float4*)(x + (size_t)(row0 + ar) * FIN + k0 + ak);
        float4 wv[2];
#pragma unroll
        for (int t2 = 0; t2 < 2; ++t2) {
            int f  = tid * 2 + t2;           // 0..511
            int kk = f >> 5;                 // 0..15
            int c  = (f & 31) << 2;          // 0..124
            const float* Wp = (c < 64) ? (Wtd + (size_t)(k0 + kk) * 64 + c)
                                       : (Wbu + (size_t)(k0 + kk) * 64 + (c - 64));
            wv[t2] = *(const float4*)Wp;
        }
        {   // swizzled transpose-write of A
            int sc = ar ^ asw;
            As[ak + 0][sc] = av.x;
            As[ak + 1][sc] = av.y;
            As[ak + 2][sc] = av.z;
            As[ak + 3][sc] = av.w;
        }
#pragma unroll
        for (int t2 = 0; t2 < 2; ++t2) {
            int f  = tid * 2 + t2;
            int kk = f >> 5;
            int c  = (f & 31) << 2;
            *(float4*)&Ws[kk][c] = wv[t2];
        }
        __syncthreads();
#pragma unroll
        for (int kk = 0; kk < 16; ++kk) {
            int sw = ((kk >> 2) & 3) << 3;
            float a[8];
            *(float4*)&a[0] = *(const float4*)&As[kk][(r0) ^ sw];
            *(float4*)&a[4] = *(const float4*)&As[kk][(r0 + 4) ^ sw];
            float4 w = *(const float4*)&Ws[kk][c0];
#pragma unroll
            for (int i = 0; i < 8; ++i) {
                acc[i][0] = fmaf(a[i], w.x, acc[i][0]);
                acc[i][1] = fmaf(a[i], w.y, acc[i][1]);
                acc[i][2] = fmaf(a[i], w.z, acc[i][2]);
                acc[i][3] = fmaf(a[i], w.w, acc[i][3]);
            }
        }
        __syncthreads();
    }
    const int cc = c0 & 63;
    unsigned short* outb   = (c0 < 64) ? XWtd   : XWbu;
    const float*    dvp    = (c0 < 64) ? dinvtd : dinvbu;
#pragma unroll
    for (int i = 0; i < 8; ++i) {
        int row = row0 + r0 + i;
        float dv = dvp[row];
        float4 v = make_float4(acc[i][0] * dv, acc[i][1] * dv,
                               acc[i][2] * dv, acc[i][3] * dv);
        *(ushort4*)(outb + (size_t)row * 64 + cc) = pack4(v);
    }
}

// ---------------------------------------------------------------------------
// RB[b][c] = sum_k relu(root[b,k]) * W2[(64+k), c]  for both branches
__global__ __launch_bounds__(128) void k_rb(const float* __restrict__ root,
                                            const float* __restrict__ W2td,
                                            const float* __restrict__ W2bu,
                                            float* __restrict__ RBtd,
                                            float* __restrict__ RBbu) {
    int b = blockIdx.x;
    int c = threadIdx.x;                 // 0..127
    const float* W2 = (c < 64) ? W2td : W2bu;
    int cc = c & 63;
    const float* rp = root + (size_t)b * FIN;
    float s = 0.f;
    for (int k = 0; k < FIN; ++k) {
        float r = fmaxf(rp[k], 0.f);
        s = fmaf(r, W2[(size_t)(64 + k) * 64 + cc], s);
    }
    (c < 64 ? RBtd : RBbu)[b * 64 + cc] = s;
}

// ---------------------------------------------------------------------------
// CSR gather over PRE-SCALED bf16 rows (xh[i] = bf16(dinv[i] * xw[i])):
//   out[i] = bias + dinv[i] * (xh[i] + sum_e xh[src])        (f32 accumulate)
// quarter-wave (16 lanes x 4 bf16 = 128 B/edge coalesced) per node.
__global__ __launch_bounds__(256) void k_gather(const int* __restrict__ rowptr,
                                                const int* __restrict__ csr,
                                                const float* __restrict__ dinv,
                                                const unsigned short* __restrict__ xh,
                                                const float* __restrict__ bias,
                                                float* __restrict__ out) {
    int t    = blockIdx.x * blockDim.x + threadIdx.x;
    int node = t >> 4;
    int li   = (t & 15) << 2;
    if (node >= N_NODES) return;
    float4 acc0 = unpack4(*(const ushort4*)(xh + (size_t)node * 64 + li)); // self
    float4 acc1 = make_float4(0.f, 0.f, 0.f, 0.f);
    int e0 = rowptr[node], e1 = rowptr[node + 1];
    int e = e0;
    for (; e + 4 <= e1; e += 4) {
        int s0 = csr[e + 0], s1 = csr[e + 1], s2 = csr[e + 2], s3 = csr[e + 3];
        float4 v0 = unpack4(*(const ushort4*)(xh + (size_t)s0 * 64 + li));
        float4 v1 = unpack4(*(const ushort4*)(xh + (size_t)s1 * 64 + li));
        float4 v2 = unpack4(*(const ushort4*)(xh + (size_t)s2 * 64 + li));
        float4 v3 = unpack4(*(const ushort4*)(xh + (size_t)s3 * 64 + li));
        acc0.x += (v0.x + v1.x) + (v2.x + v3.x);
        acc0.y += (v0.y + v1.y) + (v2.y + v3.y);
        acc0.z += (v0.z + v1.z) + (v2.z + v3.z);
        acc0.w += (v0.w + v1.w) + (v2.w + v3.w);
    }
    for (; e < e1; ++e) {
        int s = csr[e];
        float4 v = unpack4(*(const ushort4*)(xh + (size_t)s * 64 + li));
        acc1.x += v.x; acc1.y += v.y; acc1.z += v.z; acc1.w += v.w;
    }
    acc0.x += acc1.x; acc0.y += acc1.y; acc0.z += acc1.z; acc0.w += acc1.w;
    float dv = dinv[node];
    float4 bb = *(const float4*)(bias + li);
    float4 r;
    r.x = fmaf(dv, acc0.x, bb.x);
    r.y = fmaf(dv, acc0.y, bb.y);
    r.z = fmaf(dv, acc0.z, bb.z);
    r.w = fmaf(dv, acc0.w, bb.w);
    *(float4*)(out + (size_t)node * 64 + li) = r;
}

// ---------------------------------------------------------------------------
// GEMM2 fused: XW2[i,:] = bf16( dinv[i] * (relu(H1[i,:]) @ W2a + RB[batch[i],:]) )
// Same As-swizzle as gemm1.
__global__ __launch_bounds__(256) void k_gemm2(const float* __restrict__ H1,
                                               const float* __restrict__ W2,
                                               const float* __restrict__ RB,
                                               const int* __restrict__ batch,
                                               const float* __restrict__ dinv,
                                               unsigned short* __restrict__ XW2) {
    __shared__ __align__(16) float As[16][64];   // relu(H1) [k][row] swizzled
    __shared__ __align__(16) float Ws[16][64];   // W2a [k][col]
    const int tid  = threadIdx.x;
    const int row0 = blockIdx.x * 64;
    const int c0 = (tid & 15) * 4;   // 0..60
    const int r0 = (tid >> 4) * 4;   // 0..60
    float acc[4][4];
#pragma unroll
    for (int i = 0; i < 4; ++i)
#pragma unroll
        for (int j = 0; j < 4; ++j) acc[i][j] = 0.f;

    const int ar  = tid >> 2;            // 0..63
    const int ak  = (tid & 3) << 2;      // 0,4,8,12
    const int asw = (tid & 3) << 3;      // swizzle {0,8,16,24}
    const int wk  = tid >> 4;            // 0..15
    const int wc  = (tid & 15) << 2;     // 0..60

    for (int k0 = 0; k0 < FH; k0 += 16) {
        float4 av = *(const float4*)(H1 + (size_t)(row0 + ar) * 64 + k0 + ak);
        int sc = ar ^ asw;
        As[ak + 0][sc] = fmaxf(av.x, 0.f);
        As[ak + 1][sc] = fmaxf(av.y, 0.f);
        As[ak + 2][sc] = fmaxf(av.z, 0.f);
        As[ak + 3][sc] = fmaxf(av.w, 0.f);
        *(float4*)&Ws[wk][wc] = *(const float4*)(W2 + (size_t)(k0 + wk) * 64 + wc);
        __syncthreads();
#pragma unroll
        for (int kk = 0; kk < 16; ++kk) {
            int sw = ((kk >> 2) & 3) << 3;
            float4 w = *(float4*)&Ws[kk][c0];
            float4 a = *(const float4*)&As[kk][r0 ^ sw];
            acc[0][0] = fmaf(a.x, w.x, acc[0][0]); acc[0][1] = fmaf(a.x, w.y, acc[0][1]);
            acc[0][2] = fmaf(a.x, w.z, acc[0][2]); acc[0][3] = fmaf(a.x, w.w, acc[0][3]);
            acc[1][0] = fmaf(a.y, w.x, acc[1][0]); acc[1][1] = fmaf(a.y, w.y, acc[1][1]);
            acc[1][2] = fmaf(a.y, w.z, acc[1][2]); acc[1][3] = fmaf(a.y, w.w, acc[1][3]);
            acc[2][0] = fmaf(a.z, w.x, acc[2][0]); acc[2][1] = fmaf(a.z, w.y, acc[2][1]);
            acc[2][2] = fmaf(a.z, w.z, acc[2][2]); acc[2][3] = fmaf(a.z, w.w, acc[2][3]);
            acc[3][0] = fmaf(a.w, w.x, acc[3][0]); acc[3][1] = fmaf(a.w, w.y, acc[3][1]);
            acc[3][2] = fmaf(a.w, w.z, acc[3][2]); acc[3][3] = fmaf(a.w, w.w, acc[3][3]);
        }
        __syncthreads();
    }
#pragma unroll
    for (int i = 0; i < 4; ++i) {
        int row = row0 + r0 + i;
        int bg  = batch[row];
        float dv = dinv[row];
        float4 rb = *(const float4*)(RB + (size_t)bg * 64 + c0);
        float4 xw2 = make_float4((acc[i][0] + rb.x) * dv, (acc[i][1] + rb.y) * dv,
                                 (acc[i][2] + rb.z) * dv, (acc[i][3] + rb.w) * dv);
        *(ushort4*)(XW2 + (size_t)row * 64 + c0) = pack4(xw2);
    }
}

// ---------------------------------------------------------------------------
__device__ __forceinline__ int lb_search(const int* __restrict__ a, int n, int v) {
    int lo = 0, hi = n;
    while (lo < hi) {
        int m = (lo + hi) >> 1;
        if (a[m] < v) lo = m + 1; else hi = m;
    }
    return lo;
}

// Pool per graph: pooled[b][0:64]  = mean over graph nodes of relu(H2)
//                 pooled[b][64:128]= cnt>0 ? H1[rootindex[b]] : 0
__global__ __launch_bounds__(512) void k_pool(const float* __restrict__ H2,
                                              const float* __restrict__ H1,
                                              const int* __restrict__ batch,
                                              const int* __restrict__ rootindex,
                                              float* __restrict__ pooled) {
    int b    = blockIdx.x;
    int lane = threadIdx.x & 63;
    int wv   = threadIdx.x >> 6;      // 0..7
    int start = lb_search(batch, N_NODES, b);
    int end   = lb_search(batch, N_NODES, b + 1);
    float acc = 0.f;
    for (int i = start + wv; i < end; i += 8)
        acc += fmaxf(H2[(size_t)i * 64 + lane], 0.f);
    __shared__ float red[8][64];
    red[wv][lane] = acc;
    __syncthreads();
    if (wv == 0) {
        float s = 0.f;
#pragma unroll
        for (int w = 0; w < 8; ++w) s += red[w][lane];
        int cnt = end - start;
        float inv = 1.0f / fmaxf((float)cnt, 1.0f);
        pooled[b * 128 + lane] = s * inv;
        float rootv = (cnt > 0) ? H1[(size_t)rootindex[b] * 64 + lane] : 0.f;
        pooled[b * 128 + 64 + lane] = rootv;
    }
}

// ---------------------------------------------------------------------------
// Final FC + log_softmax.  feat = [pooled_bu | pooled_td]  (bu FIRST)
__global__ __launch_bounds__(128) void k_final(const float* __restrict__ ptd,
                                               const float* __restrict__ pbu,
                                               const float* __restrict__ fcW,
                                               const float* __restrict__ fcb,
                                               float* __restrict__ out) {
    int b = threadIdx.x;
    if (b >= NB) return;
    float l[4] = {fcb[0], fcb[1], fcb[2], fcb[3]};
    for (int j = 0; j < 256; ++j) {
        float f = (j < 128) ? pbu[b * 128 + j] : ptd[b * 128 + (j - 128)];
#pragma unroll
        for (int c = 0; c < 4; ++c) l[c] = fmaf(f, fcW[j * 4 + c], l[c]);
    }
    float m = fmaxf(fmaxf(l[0], l[1]), fmaxf(l[2], l[3]));
    float s = expf(l[0] - m) + expf(l[1] - m) + expf(l[2] - m) + expf(l[3] - m);
    float ls = logf(s);
#pragma unroll
    for (int c = 0; c < 4; ++c) out[b * 4 + c] = l[c] - m - ls;
}

// ---------------------------------------------------------------------------
extern "C" void kernel_launch(void* const* d_in, const int* in_sizes, int n_in,
                              void* d_out, int out_size, void* d_ws, size_t ws_size,
                              hipStream_t stream) {
    const float* x     = (const float*)d_in[0];
    const int*   ei    = (const int*)d_in[1];    // [2,E]: src, dst
    const int*   bei   = (const int*)d_in[2];
    const int*   batch = (const int*)d_in[3];
    const int*   rooti = (const int*)d_in[4];
    const float* root  = (const float*)d_in[5];
    const float* W1td  = (const float*)d_in[6];
    const float* b1td  = (const float*)d_in[7];
    const float* W2td  = (const float*)d_in[8];
    const float* b2td  = (const float*)d_in[9];
    const float* W1bu  = (const float*)d_in[10];
    const float* b1bu  = (const float*)d_in[11];
    const float* W2bu  = (const float*)d_in[12];
    const float* b2bu  = (const float*)d_in[13];
    const float* fcW   = (const float*)d_in[14];
    const float* fcb   = (const float*)d_in[15];
    float* out = (float*)d_out;

    char* ws = (char*)d_ws;
    size_t o = 0;
    const size_t NF = (size_t)N_NODES * 64;
    auto alloc_f = [&](size_t n) { float* p = (float*)(ws + o); o += n * 4; return p; };
    auto alloc_h = [&](size_t n) { unsigned short* p = (unsigned short*)(ws + o); o += n * 2; return p; };
    auto alloc_i = [&](size_t n) { int*   p = (int*)  (ws + o); o += n * 4; return p; };

    unsigned short* XWtd = alloc_h(NF);              // bf16 rows (also reused as XW2)
    unsigned short* XWbu = alloc_h(NF);
    float* H1     = alloc_f(NF);
    float* H2     = alloc_f(NF);
    float* dinvtd = alloc_f(N_NODES);
    float* dinvbu = alloc_f(N_NODES);
    float* RBtd   = alloc_f((size_t)NB * 64);
    float* RBbu   = alloc_f((size_t)NB * 64);
    float* pooltd = alloc_f((size_t)NB * 128);
    float* poolbu = alloc_f((size_t)NB * 128);
    int* degi     = alloc_i(2 * (size_t)N_NODES);    // td | bu
    int* rp_td    = alloc_i(N_NODES + 1);
    int* rp_bu    = alloc_i(N_NODES + 1);
    int* cur_td   = alloc_i(N_NODES);
    int* cur_bu   = alloc_i(N_NODES);
    int* bsum     = alloc_i(256);
    int* boff     = alloc_i(256);
    int* csr_td   = alloc_i(N_EDGES);
    int* csr_bu   = alloc_i(N_EDGES);

    const int eb = (N_EDGES + 255) / 256;            // 12500

    // degrees + dinv
    hipMemsetAsync(degi, 0, 2 * (size_t)N_NODES * sizeof(int), stream);
    k_degi<<<eb, 256, 0, stream>>>(ei + N_EDGES, bei + N_EDGES, degi);
    k_dinv<<<(2 * N_NODES + 255) / 256, 256, 0, stream>>>(degi, dinvtd);

    // CSR build (td then bu; scan scratch reused — stream-ordered)
    k_scanA<<<NBLK, 256, 0, stream>>>(degi, bsum);
    k_scanB<<<1, 256, 0, stream>>>(bsum, boff);
    k_scanC<<<NBLK, 256, 0, stream>>>(degi, boff, rp_td, cur_td);
    k_fill<<<eb, 256, 0, stream>>>(ei, ei + N_EDGES, cur_td, csr_td);

    k_scanA<<<NBLK, 256, 0, stream>>>(degi + N_NODES, bsum);
    k_scanB<<<1, 256, 0, stream>>>(bsum, boff);
    k_scanC<<<NBLK, 256, 0, stream>>>(degi + N_NODES, boff, rp_bu, cur_bu);
    k_fill<<<eb, 256, 0, stream>>>(bei, bei + N_EDGES, cur_bu, csr_bu);

    // big fused matmul + dinv prescale + bf16 pack + root-projection
    k_gemm1<<<N_NODES / 64, 256, 0, stream>>>(x, W1td, W1bu, dinvtd, dinvbu, XWtd, XWbu);
    k_rb<<<NB, 128, 0, stream>>>(root, W2td, W2bu, RBtd, RBbu);

    const int gb = (N_NODES * 16) / 256;             // 12500

    // ---- td branch ----
    k_gather<<<gb, 256, 0, stream>>>(rp_td, csr_td, dinvtd, XWtd, b1td, H1);
    k_gemm2<<<N_NODES / 64, 256, 0, stream>>>(H1, W2td, RBtd, batch, dinvtd, XWtd /*XW2*/);
    k_gather<<<gb, 256, 0, stream>>>(rp_td, csr_td, dinvtd, XWtd, b2td, H2);
    k_pool<<<NB, 512, 0, stream>>>(H2, H1, batch, rooti, pooltd);

    // ---- bu branch ----
    k_gather<<<gb, 256, 0, stream>>>(rp_bu, csr_bu, dinvbu, XWbu, b1bu, H1);
    k_gemm2<<<N_NODES / 64, 256, 0, stream>>>(H1, W2bu, RBbu, batch, dinvbu, XWbu /*XW2*/);
    k_gather<<<gb, 256, 0, stream>>>(rp_bu, csr_bu, dinvbu, XWbu, b2bu, H2);
    k_pool<<<NB, 512, 0, stream>>>(H2, H1, batch, rooti, poolbu);

    // ---- head ----
    k_final<<<1, 128, 0, stream>>>(pooltd, poolbu, fcW, fcb, out);
}

// Round 5
// 2119.408 us; speedup vs baseline: 1.2988x; 1.1806x over previous
//
#include <hip/hip_runtime.h>
#include <math.h>

#define N_NODES 200000
#define N_EDGES 3200000
#define NB      128
#define FIN     768
#define FH      64      // HID == OUT == 64
#define NC      4
#define GB      12500                       // gather blocks per branch
#define NB2     (N_NODES / 64)              // gemm2 blocks per branch (3125)

#define SCAN_TILE 1024                      // 256 threads x 4 elems
#define NBLK ((N_NODES + SCAN_TILE - 1) / SCAN_TILE)   // 196 (<=256 required)

typedef _Float16 f16;
typedef __attribute__((ext_vector_type(8))) _Float16 f16x8;
typedef __attribute__((ext_vector_type(4))) float f32x4;

// ---------------------------------------------------------------------------
// bf16 helpers (storage format for gathered arrays; f32 compute throughout)
__device__ __forceinline__ unsigned short f2bf(float f) {
    unsigned int u = __float_as_uint(f);
    u += 0x7fffu + ((u >> 16) & 1u);      // round-to-nearest-even
    return (unsigned short)(u >> 16);
}
__device__ __forceinline__ float4 unpack4(ushort4 h) {
    float4 f;
    f.x = __uint_as_float((unsigned int)h.x << 16);
    f.y = __uint_as_float((unsigned int)h.y << 16);
    f.z = __uint_as_float((unsigned int)h.z << 16);
    f.w = __uint_as_float((unsigned int)h.w << 16);
    return f;
}

// ---------------------------------------------------------------------------
// Integer in-degree of dst for both edge sets. degi[0..N)=td, [N..2N)=bu.
__global__ __launch_bounds__(256) void k_degi(const int* __restrict__ dst_td,
                                              const int* __restrict__ dst_bu,
                                              int* __restrict__ degi) {
    int i = blockIdx.x * blockDim.x + threadIdx.x;
    if (i < N_EDGES) {
        atomicAdd(degi + dst_td[i], 1);
        atomicAdd(degi + N_NODES + dst_bu[i], 1);
    }
}

// dinv = rsqrt(deg + 1)   (self-loop included; always > 0)
__global__ __launch_bounds__(256) void k_dinv(const int* __restrict__ degi,
                                              float* __restrict__ dv) {
    int i = blockIdx.x * blockDim.x + threadIdx.x;
    if (i < 2 * N_NODES) dv[i] = rsqrtf((float)degi[i] + 1.0f);
}

// ---------------------------------------------------------------------------
// Prefix-scan of degrees -> rowptr (exclusive), cursor (copy of rowptr).
__global__ __launch_bounds__(256) void k_scanA(const int* __restrict__ deg,
                                               int* __restrict__ bsum) {
    __shared__ int sh[256];
    int t = threadIdx.x, b = blockIdx.x;
    int base = b * SCAN_TILE + t * 4;
    int s = 0;
#pragma unroll
    for (int j = 0; j < 4; ++j) {
        int idx = base + j;
        if (idx < N_NODES) s += deg[idx];
    }
    sh[t] = s;
    __syncthreads();
    for (int off = 128; off > 0; off >>= 1) {
        if (t < off) sh[t] += sh[t + off];
        __syncthreads();
    }
    if (t == 0) bsum[b] = sh[0];
}

__global__ __launch_bounds__(256) void k_scanB(const int* __restrict__ bsum,
                                               int* __restrict__ boff) {
    __shared__ int sh[256];
    int t = threadIdx.x;
    int v = (t < NBLK) ? bsum[t] : 0;
    sh[t] = v;
    __syncthreads();
    for (int off = 1; off < 256; off <<= 1) {
        int a = (t >= off) ? sh[t - off] : 0;
        __syncthreads();
        sh[t] += a;
        __syncthreads();
    }
    if (t < NBLK) boff[t] = sh[t] - v;   // exclusive
}

__global__ __launch_bounds__(256) void k_scanC(const int* __restrict__ deg,
                                               const int* __restrict__ boff,
                                               int* __restrict__ rowptr,
                                               int* __restrict__ cursor) {
    __shared__ int sh[256];
    int t = threadIdx.x, b = blockIdx.x;
    int base = b * SCAN_TILE + t * 4;
    int v[4];
    int tot = 0;
#pragma unroll
    for (int j = 0; j < 4; ++j) {
        int idx = base + j;
        v[j] = (idx < N_NODES) ? deg[idx] : 0;
        tot += v[j];
    }
    sh[t] = tot;
    __syncthreads();
    for (int off = 1; off < 256; off <<= 1) {
        int a = (t >= off) ? sh[t - off] : 0;
        __syncthreads();
        sh[t] += a;
        __syncthreads();
    }
    int run = boff[b] + sh[t] - tot;     // global exclusive prefix at base
#pragma unroll
    for (int j = 0; j < 4; ++j) {
        int idx = base + j;
        if (idx < N_NODES) {
            rowptr[idx] = run;
            cursor[idx] = run;
            run += v[j];
        }
    }
    if (b == 0 && t == 0) rowptr[N_NODES] = N_EDGES;
}

// Counting-sort edges into CSR by dst, both branches fused in one launch.
__global__ __launch_bounds__(256) void k_fill2(const int* __restrict__ ei,
                                               const int* __restrict__ bei,
                                               int* __restrict__ cur_td,
                                               int* __restrict__ cur_bu,
                                               int* __restrict__ csr_td,
                                               int* __restrict__ csr_bu) {
    int i = blockIdx.x * blockDim.x + threadIdx.x;
    int e = (i >= N_EDGES) ? i - N_EDGES : i;
    const int* src = (i >= N_EDGES) ? bei : ei;
    int* cursor    = (i >= N_EDGES) ? cur_bu : cur_td;
    int* csr       = (i >= N_EDGES) ? csr_bu : csr_td;
    if (e < N_EDGES) {
        int d = src[N_EDGES + e];        // dst
        int pos = atomicAdd(cursor + d, 1);
        csr[pos] = src[e];
    }
}

// ---------------------------------------------------------------------------
// Pack W1td|W1bu (f32 768x64 each) into f16 MFMA B-fragment order:
// Wp[((c*24 + kb)*64 + l)*8 + i] = W[kb*32 + (l>>4)*8 + i][c*16 + (l&15)]
__global__ __launch_bounds__(256) void k_wpack(const float* __restrict__ Wtd,
                                               const float* __restrict__ Wbu,
                                               f16* __restrict__ Wp) {
    int tid = blockIdx.x * 256 + threadIdx.x;   // 0..12287
    if (tid >= 8 * 24 * 64) return;
    int c  = tid / (24 * 64);
    int kb = (tid / 64) % 24;
    int l  = tid & 63;
    int col = c * 16 + (l & 15);
    int k0  = kb * 32 + (l >> 4) * 8;
    const float* Wsrc = (col < 64) ? (Wtd + col) : (Wbu + (col - 64));
    f16 v[8];
#pragma unroll
    for (int i = 0; i < 8; ++i) v[i] = (f16)Wsrc[(size_t)(k0 + i) * 64];
    *(f16x8*)(Wp + (size_t)tid * 8) = *(f16x8*)v;
}

// ---------------------------------------------------------------------------
// GEMM1 via MFMA f16: XWtd = bf16(dinvtd[i]*(x@W1td)), XWbu likewise.
// LDS-free: A-frags read directly from global x (f32 -> f16 in-reg), B-frags
// from the packed L2-resident Wp. Block = 4 waves x 32 rows = 128 rows; per
// wave: 2 row-tiles x 8 col-tiles of 16x16x32 MFMA over 24 K-steps.
// mfma_f32_16x16x32_f16 layouts (m89-verified family):
//   A: row=l&15, k=8*(l>>4)+i ; B: col=l&15, k=8*(l>>4)+i
//   D: col=l&15, row=(l>>4)*4+j
__global__ __launch_bounds__(256) void k_gemm1(const float* __restrict__ x,
                                               const f16* __restrict__ Wp,
                                               const float* __restrict__ dinvtd,
                                               const float* __restrict__ dinvbu,
                                               unsigned short* __restrict__ XWtd,
                                               unsigned short* __restrict__ XWbu) {
    const int tid = threadIdx.x;
    const int wv  = tid >> 6;
    const int l   = tid & 63;
    const int lr  = l & 15;
    const int lh  = l >> 4;
    const int row_base = blockIdx.x * 128 + wv * 32;

    const float* xr[2];
#pragma unroll
    for (int rt = 0; rt < 2; ++rt) {
        int ar = row_base + rt * 16 + lr;
        if (ar > N_NODES - 1) ar = N_NODES - 1;     // clamp tail (stores guarded)
        xr[rt] = x + (size_t)ar * FIN + lh * 8;
    }

    f32x4 acc[2][8];
#pragma unroll
    for (int rt = 0; rt < 2; ++rt)
#pragma unroll
        for (int c = 0; c < 8; ++c) acc[rt][c] = (f32x4){0.f, 0.f, 0.f, 0.f};

    float4 na0[2], na1[2];
#pragma unroll
    for (int rt = 0; rt < 2; ++rt) {
        na0[rt] = *(const float4*)(xr[rt]);
        na1[rt] = *(const float4*)(xr[rt] + 4);
    }

    for (int kb = 0; kb < 24; ++kb) {
        f16x8 af[2];
#pragma unroll
        for (int rt = 0; rt < 2; ++rt) {
            float4 c0 = na0[rt], c1 = na1[rt];
            af[rt][0] = (f16)c0.x; af[rt][1] = (f16)c0.y;
            af[rt][2] = (f16)c0.z; af[rt][3] = (f16)c0.w;
            af[rt][4] = (f16)c1.x; af[rt][5] = (f16)c1.y;
            af[rt][6] = (f16)c1.z; af[rt][7] = (f16)c1.w;
        }
        if (kb < 23) {
#pragma unroll
            for (int rt = 0; rt < 2; ++rt) {
                na0[rt] = *(const float4*)(xr[rt] + (kb + 1) * 32);
                na1[rt] = *(const float4*)(xr[rt] + (kb + 1) * 32 + 4);
            }
        }
        const f16* wb = Wp + ((size_t)kb * 64 + l) * 8;
#pragma unroll
        for (int c = 0; c < 8; ++c) {
            f16x8 bf = *(const f16x8*)(wb + (size_t)c * (24 * 64 * 8));
            acc[0][c] = __builtin_amdgcn_mfma_f32_16x16x32_f16(af[0], bf, acc[0][c], 0, 0, 0);
            acc[1][c] = __builtin_amdgcn_mfma_f32_16x16x32_f16(af[1], bf, acc[1][c], 0, 0, 0);
        }
    }
#pragma unroll
    for (int rt = 0; rt < 2; ++rt) {
#pragma unroll
        for (int j = 0; j < 4; ++j) {
            int r = row_base + rt * 16 + lh * 4 + j;
            if (r < N_NODES) {
                float dtd = dinvtd[r], dbu = dinvbu[r];
#pragma unroll
                for (int c = 0; c < 8; ++c) {
                    float v = acc[rt][c][j] * (c < 4 ? dtd : dbu);
                    unsigned short* ob = (c < 4) ? XWtd : XWbu;
                    ob[(size_t)r * 64 + (c & 3) * 16 + lr] = f2bf(v);
                }
            }
        }
    }
}

// ---------------------------------------------------------------------------
// RB[b][c] = sum_k relu(root[b,k]) * W2[(64+k), c]  for both branches
__global__ __launch_bounds__(128) void k_rb(const float* __restrict__ root,
                                            const float* __restrict__ W2td,
                                            const float* __restrict__ W2bu,
                                            float* __restrict__ RBtd,
                                            float* __restrict__ RBbu) {
    int b = blockIdx.x;
    int c = threadIdx.x;                 // 0..127
    const float* W2 = (c < 64) ? W2td : W2bu;
    int cc = c & 63;
    const float* rp = root + (size_t)b * FIN;
    float s = 0.f;
    for (int k = 0; k < FIN; ++k) {
        float r = fmaxf(rp[k], 0.f);
        s = fmaf(r, W2[(size_t)(64 + k) * 64 + cc], s);
    }
    (c < 64 ? RBtd : RBbu)[b * 64 + cc] = s;
}

// ---------------------------------------------------------------------------
// Fused td+bu CSR gather (conv1) over pre-scaled bf16 rows:
//   H1[i] = bias + dinv[i] * (xh[i] + sum_e xh[src])    (f32 out, pre-relu)
__global__ __launch_bounds__(256) void k_gather1(const int* __restrict__ rp_td,
                                                 const int* __restrict__ csr_td,
                                                 const int* __restrict__ rp_bu,
                                                 const int* __restrict__ csr_bu,
                                                 const float* __restrict__ dinvtd,
                                                 const float* __restrict__ dinvbu,
                                                 const unsigned short* __restrict__ XWtd,
                                                 const unsigned short* __restrict__ XWbu,
                                                 const float* __restrict__ b1td,
                                                 const float* __restrict__ b1bu,
                                                 float* __restrict__ H1td,
                                                 float* __restrict__ H1bu) {
    const bool bu = blockIdx.x >= GB;
    const int bid = bu ? blockIdx.x - GB : blockIdx.x;
    const int* rowptr = bu ? rp_bu : rp_td;
    const int* csr    = bu ? csr_bu : csr_td;
    const float* dinv = bu ? dinvbu : dinvtd;
    const unsigned short* xh = bu ? XWbu : XWtd;
    const float* bias = bu ? b1bu : b1td;
    float* out        = bu ? H1bu : H1td;

    int t    = bid * blockDim.x + threadIdx.x;
    int node = t >> 4;
    int li   = (t & 15) << 2;
    float4 acc0 = unpack4(*(const ushort4*)(xh + (size_t)node * 64 + li)); // self
    float4 acc1 = make_float4(0.f, 0.f, 0.f, 0.f);
    int e0 = rowptr[node], e1 = rowptr[node + 1];
    int e = e0;
    for (; e + 4 <= e1; e += 4) {
        int s0 = csr[e + 0], s1 = csr[e + 1], s2 = csr[e + 2], s3 = csr[e + 3];
        float4 v0 = unpack4(*(const ushort4*)(xh + (size_t)s0 * 64 + li));
        float4 v1 = unpack4(*(const ushort4*)(xh + (size_t)s1 * 64 + li));
        float4 v2 = unpack4(*(const ushort4*)(xh + (size_t)s2 * 64 + li));
        float4 v3 = unpack4(*(const ushort4*)(xh + (size_t)s3 * 64 + li));
        acc0.x += (v0.x + v1.x) + (v2.x + v3.x);
        acc0.y += (v0.y + v1.y) + (v2.y + v3.y);
        acc0.z += (v0.z + v1.z) + (v2.z + v3.z);
        acc0.w += (v0.w + v1.w) + (v2.w + v3.w);
    }
    for (; e < e1; ++e) {
        int s = csr[e];
        float4 v = unpack4(*(const ushort4*)(xh + (size_t)s * 64 + li));
        acc1.x += v.x; acc1.y += v.y; acc1.z += v.z; acc1.w += v.w;
    }
    acc0.x += acc1.x; acc0.y += acc1.y; acc0.z += acc1.z; acc0.w += acc1.w;
    float dv = dinv[node];
    float4 bb = *(const float4*)(bias + li);
    float4 r;
    r.x = fmaf(dv, acc0.x, bb.x);
    r.y = fmaf(dv, acc0.y, bb.y);
    r.z = fmaf(dv, acc0.z, bb.z);
    r.w = fmaf(dv, acc0.w, bb.w);
    *(float4*)(out + (size_t)node * 64 + li) = r;
}

// ---------------------------------------------------------------------------
// Fused td+bu GEMM2: XW2[i,:] = bf16(dinv[i]*(relu(H1[i,:])@W2a + RB[batch[i],:]))
__global__ __launch_bounds__(256) void k_gemm2(const float* __restrict__ H1td,
                                               const float* __restrict__ H1bu,
                                               const float* __restrict__ W2td,
                                               const float* __restrict__ W2bu,
                                               const float* __restrict__ RBtd,
                                               const float* __restrict__ RBbu,
                                               const int* __restrict__ batch,
                                               const float* __restrict__ dinvtd,
                                               const float* __restrict__ dinvbu,
                                               unsigned short* __restrict__ XW2td,
                                               unsigned short* __restrict__ XW2bu) {
    const bool bu = blockIdx.x >= NB2;
    const int bid = bu ? blockIdx.x - NB2 : blockIdx.x;
    const float* H1  = bu ? H1bu : H1td;
    const float* W2  = bu ? W2bu : W2td;
    const float* RB  = bu ? RBbu : RBtd;
    const float* dinv = bu ? dinvbu : dinvtd;
    unsigned short* XW2 = bu ? XW2bu : XW2td;

    __shared__ __align__(16) float As[16][64];   // relu(H1) [k][row] swizzled
    __shared__ __align__(16) float Ws[16][64];   // W2a [k][col]
    const int tid  = threadIdx.x;
    const int row0 = bid * 64;
    const int c0 = (tid & 15) * 4;   // 0..60
    const int r0 = (tid >> 4) * 4;   // 0..60
    float acc[4][4];
#pragma unroll
    for (int i = 0; i < 4; ++i)
#pragma unroll
        for (int j = 0; j < 4; ++j) acc[i][j] = 0.f;

    const int ar  = tid >> 2;            // 0..63
    const int ak  = (tid & 3) << 2;      // 0,4,8,12
    const int asw = (tid & 3) << 3;      // swizzle {0,8,16,24}
    const int wk  = tid >> 4;            // 0..15
    const int wc  = (tid & 15) << 2;     // 0..60

    for (int k0 = 0; k0 < FH; k0 += 16) {
        float4 av = *(const float4*)(H1 + (size_t)(row0 + ar) * 64 + k0 + ak);
        int sc = ar ^ asw;
        As[ak + 0][sc] = fmaxf(av.x, 0.f);
        As[ak + 1][sc] = fmaxf(av.y, 0.f);
        As[ak + 2][sc] = fmaxf(av.z, 0.f);
        As[ak + 3][sc] = fmaxf(av.w, 0.f);
        *(float4*)&Ws[wk][wc] = *(const float4*)(W2 + (size_t)(k0 + wk) * 64 + wc);
        __syncthreads();
#pragma unroll
        for (int kk = 0; kk < 16; ++kk) {
            int sw = ((kk >> 2) & 3) << 3;
            float4 w = *(float4*)&Ws[kk][c0];
            float4 a = *(const float4*)&As[kk][r0 ^ sw];
            acc[0][0] = fmaf(a.x, w.x, acc[0][0]); acc[0][1] = fmaf(a.x, w.y, acc[0][1]);
            acc[0][2] = fmaf(a.x, w.z, acc[0][2]); acc[0][3] = fmaf(a.x, w.w, acc[0][3]);
            acc[1][0] = fmaf(a.y, w.x, acc[1][0]); acc[1][1] = fmaf(a.y, w.y, acc[1][1]);
            acc[1][2] = fmaf(a.y, w.z, acc[1][2]); acc[1][3] = fmaf(a.y, w.w, acc[1][3]);
            acc[2][0] = fmaf(a.z, w.x, acc[2][0]); acc[2][1] = fmaf(a.z, w.y, acc[2][1]);
            acc[2][2] = fmaf(a.z, w.z, acc[2][2]); acc[2][3] = fmaf(a.z, w.w, acc[2][3]);
            acc[3][0] = fmaf(a.w, w.x, acc[3][0]); acc[3][1] = fmaf(a.w, w.y, acc[3][1]);
            acc[3][2] = fmaf(a.w, w.z, acc[3][2]); acc[3][3] = fmaf(a.w, w.w, acc[3][3]);
        }
        __syncthreads();
    }
#pragma unroll
    for (int i = 0; i < 4; ++i) {
        int row = row0 + r0 + i;
        int bg  = batch[row];
        float dv = dinv[row];
        float4 rb = *(const float4*)(RB + (size_t)bg * 64 + c0);
        float v0 = (acc[i][0] + rb.x) * dv, v1 = (acc[i][1] + rb.y) * dv;
        float v2 = (acc[i][2] + rb.z) * dv, v3 = (acc[i][3] + rb.w) * dv;
        ushort4 h; h.x = f2bf(v0); h.y = f2bf(v1); h.z = f2bf(v2); h.w = f2bf(v3);
        *(ushort4*)(XW2 + (size_t)row * 64 + c0) = h;
    }
}

// ---------------------------------------------------------------------------
// Fused td+bu gather(conv2) + relu + segment-sum pooling (H2 never stored):
//   r = relu(bias + dinv*(self + sum_e)) ; poolsum[branch][batch[node]] += r
// Block = 16 nodes; block-local run-reduction => ~1 atomic per col per block.
__global__ __launch_bounds__(256) void k_g2pool(const int* __restrict__ rp_td,
                                                const int* __restrict__ csr_td,
                                                const int* __restrict__ rp_bu,
                                                const int* __restrict__ csr_bu,
                                                const float* __restrict__ dinvtd,
                                                const float* __restrict__ dinvbu,
                                                const unsigned short* __restrict__ XW2td,
                                                const unsigned short* __restrict__ XW2bu,
                                                const float* __restrict__ b2td,
                                                const float* __restrict__ b2bu,
                                                const int* __restrict__ batch,
                                                float* __restrict__ poolsum) {
    const bool bu = blockIdx.x >= GB;
    const int bid = bu ? blockIdx.x - GB : blockIdx.x;
    const int* rowptr = bu ? rp_bu : rp_td;
    const int* csr    = bu ? csr_bu : csr_td;
    const float* dinv = bu ? dinvbu : dinvtd;
    const unsigned short* xh = bu ? XW2bu : XW2td;
    const float* bias = bu ? b2bu : b2td;
    float* ps = poolsum + (bu ? NB * 64 : 0);

    int t    = bid * blockDim.x + threadIdx.x;
    int node = t >> 4;
    int li   = (t & 15) << 2;
    float4 acc0 = unpack4(*(const ushort4*)(xh + (size_t)node * 64 + li)); // self
    int e0 = rowptr[node], e1 = rowptr[node + 1];
    int e = e0;
    for (; e + 4 <= e1; e += 4) {
        int s0 = csr[e + 0], s1 = csr[e + 1], s2 = csr[e + 2], s3 = csr[e + 3];
        float4 v0 = unpack4(*(const ushort4*)(xh + (size_t)s0 * 64 + li));
        float4 v1 = unpack4(*(const ushort4*)(xh + (size_t)s1 * 64 + li));
        float4 v2 = unpack4(*(const ushort4*)(xh + (size_t)s2 * 64 + li));
        float4 v3 = unpack4(*(const ushort4*)(xh + (size_t)s3 * 64 + li));
        acc0.x += (v0.x + v1.x) + (v2.x + v3.x);
        acc0.y += (v0.y + v1.y) + (v2.y + v3.y);
        acc0.z += (v0.z + v1.z) + (v2.z + v3.z);
        acc0.w += (v0.w + v1.w) + (v2.w + v3.w);
    }
    for (; e < e1; ++e) {
        int s = csr[e];
        float4 v = unpack4(*(const ushort4*)(xh + (size_t)s * 64 + li));
        acc0.x += v.x; acc0.y += v.y; acc0.z += v.z; acc0.w += v.w;
    }
    float dv = dinv[node];
    float4 bb = *(const float4*)(bias + li);
    float4 r;
    r.x = fmaxf(fmaf(dv, acc0.x, bb.x), 0.f);
    r.y = fmaxf(fmaf(dv, acc0.y, bb.y), 0.f);
    r.z = fmaxf(fmaf(dv, acc0.z, bb.z), 0.f);
    r.w = fmaxf(fmaf(dv, acc0.w, bb.w), 0.f);

    __shared__ __align__(16) float red[16][72];
    __shared__ int bat[16];
    int slot = threadIdx.x >> 4;
    *(float4*)&red[slot][li] = r;
    if ((threadIdx.x & 15) == 0) bat[slot] = batch[node];
    __syncthreads();
    if (threadIdx.x < 64) {
        int c = threadIdx.x;
        float run = red[0][c];
        int cur = bat[0];
        for (int i = 1; i < 16; ++i) {
            int bi = bat[i];
            if (bi != cur) {
                atomicAdd(&ps[cur * 64 + c], run);
                run = 0.f;
                cur = bi;
            }
            run += red[i][c];
        }
        atomicAdd(&ps[cur * 64 + c], run);
    }
}

// ---------------------------------------------------------------------------
__device__ __forceinline__ int lb_search(const int* __restrict__ a, int n, int v) {
    int lo = 0, hi = n;
    while (lo < hi) {
        int m = (lo + hi) >> 1;
        if (a[m] < v) lo = m + 1; else hi = m;
    }
    return lo;
}

// Final: feat = [bu_mean(64)|bu_root(64)|td_mean(64)|td_root(64)] @ fcW + fcb
// -> log_softmax.  Root rows come straight from H1; mean = poolsum/cnt.
__global__ __launch_bounds__(128) void k_final(const float* __restrict__ poolsum,
                                               const float* __restrict__ H1td,
                                               const float* __restrict__ H1bu,
                                               const int* __restrict__ batch,
                                               const int* __restrict__ rooti,
                                               const float* __restrict__ fcW,
                                               const float* __restrict__ fcb,
                                               float* __restrict__ out) {
    int b = threadIdx.x;
    if (b >= NB) return;
    int start = lb_search(batch, N_NODES, b);
    int end   = lb_search(batch, N_NODES, b + 1);
    int cnt   = end - start;
    float inv = 1.0f / fmaxf((float)cnt, 1.0f);
    int ri = rooti[b];
    float l[4] = {fcb[0], fcb[1], fcb[2], fcb[3]};
    for (int j = 0; j < 256; ++j) {
        float f;
        if (j < 64)       f = poolsum[NB * 64 + b * 64 + j] * inv;                  // bu mean
        else if (j < 128) f = (cnt > 0) ? H1bu[(size_t)ri * 64 + (j - 64)] : 0.f;   // bu root
        else if (j < 192) f = poolsum[b * 64 + (j - 128)] * inv;                    // td mean
        else              f = (cnt > 0) ? H1td[(size_t)ri * 64 + (j - 192)] : 0.f;  // td root
#pragma unroll
        for (int c = 0; c < 4; ++c) l[c] = fmaf(f, fcW[j * 4 + c], l[c]);
    }
    float m = fmaxf(fmaxf(l[0], l[1]), fmaxf(l[2], l[3]));
    float s = expf(l[0] - m) + expf(l[1] - m) + expf(l[2] - m) + expf(l[3] - m);
    float ls = logf(s);
#pragma unroll
    for (int c = 0; c < 4; ++c) out[b * 4 + c] = l[c] - m - ls;
}

// ---------------------------------------------------------------------------
extern "C" void kernel_launch(void* const* d_in, const int* in_sizes, int n_in,
                              void* d_out, int out_size, void* d_ws, size_t ws_size,
                              hipStream_t stream) {
    const float* x     = (const float*)d_in[0];
    const int*   ei    = (const int*)d_in[1];    // [2,E]: src, dst
    const int*   bei   = (const int*)d_in[2];
    const int*   batch = (const int*)d_in[3];
    const int*   rooti = (const int*)d_in[4];
    const float* root  = (const float*)d_in[5];
    const float* W1td  = (const float*)d_in[6];
    const float* b1td  = (const float*)d_in[7];
    const float* W2td  = (const float*)d_in[8];
    const float* b2td  = (const float*)d_in[9];
    const float* W1bu  = (const float*)d_in[10];
    const float* b1bu  = (const float*)d_in[11];
    const float* W2bu  = (const float*)d_in[12];
    const float* b2bu  = (const float*)d_in[13];
    const float* fcW   = (const float*)d_in[14];
    const float* fcb   = (const float*)d_in[15];
    float* out = (float*)d_out;

    char* ws = (char*)d_ws;
    size_t o = 0;
    const size_t NF = (size_t)N_NODES * 64;
    auto alloc_f = [&](size_t n) { float* p = (float*)(ws + o); o += n * 4; return p; };
    auto alloc_h = [&](size_t n) { unsigned short* p = (unsigned short*)(ws + o); o += n * 2; return p; };
    auto alloc_i = [&](size_t n) { int*   p = (int*)  (ws + o); o += n * 4; return p; };

    unsigned short* XWtd = alloc_h(NF);              // bf16 rows (reused as XW2)
    unsigned short* XWbu = alloc_h(NF);
    float* H1td   = alloc_f(NF);
    float* H1bu   = alloc_f(NF);
    f16*   Wp     = (f16*)alloc_h(8 * 24 * 64 * 8);  // packed W1 f16 frags
    float* dinvtd = alloc_f(N_NODES);
    float* dinvbu = alloc_f(N_NODES);                // contiguous after dinvtd
    float* RBtd   = alloc_f((size_t)NB * 64);
    float* RBbu   = alloc_f((size_t)NB * 64);
    float* poolsum = alloc_f(2 * (size_t)NB * 64);   // [td|bu][NB][64]
    int* degi     = alloc_i(2 * (size_t)N_NODES);    // td | bu
    int* rp_td    = alloc_i(N_NODES + 1);
    int* rp_bu    = alloc_i(N_NODES + 1);
    int* cur_td   = alloc_i(N_NODES);
    int* cur_bu   = alloc_i(N_NODES);
    int* bsum     = alloc_i(256);
    int* boff     = alloc_i(256);
    int* csr_td   = alloc_i(N_EDGES);
    int* csr_bu   = alloc_i(N_EDGES);

    const int eb = (N_EDGES + 255) / 256;            // 12500

    // W pack (no deps)
    k_wpack<<<48, 256, 0, stream>>>(W1td, W1bu, Wp);

    // degrees + dinv
    hipMemsetAsync(degi, 0, 2 * (size_t)N_NODES * sizeof(int), stream);
    k_degi<<<eb, 256, 0, stream>>>(ei + N_EDGES, bei + N_EDGES, degi);
    k_dinv<<<(2 * N_NODES + 255) / 256, 256, 0, stream>>>(degi, dinvtd);

    // CSR build (scans serial per branch; fills fused)
    k_scanA<<<NBLK, 256, 0, stream>>>(degi, bsum);
    k_scanB<<<1, 256, 0, stream>>>(bsum, boff);
    k_scanC<<<NBLK, 256, 0, stream>>>(degi, boff, rp_td, cur_td);
    k_scanA<<<NBLK, 256, 0, stream>>>(degi + N_NODES, bsum);
    k_scanB<<<1, 256, 0, stream>>>(bsum, boff);
    k_scanC<<<NBLK, 256, 0, stream>>>(degi + N_NODES, boff, rp_bu, cur_bu);
    k_fill2<<<2 * eb, 256, 0, stream>>>(ei, bei, cur_td, cur_bu, csr_td, csr_bu);

    // MFMA matmul + dinv prescale + bf16 pack; root projection
    k_gemm1<<<(N_NODES + 127) / 128, 256, 0, stream>>>(x, Wp, dinvtd, dinvbu, XWtd, XWbu);
    k_rb<<<NB, 128, 0, stream>>>(root, W2td, W2bu, RBtd, RBbu);
    hipMemsetAsync(poolsum, 0, 2 * (size_t)NB * 64 * sizeof(float), stream);

    // conv1 (both branches fused)
    k_gather1<<<2 * GB, 256, 0, stream>>>(rp_td, csr_td, rp_bu, csr_bu,
                                          dinvtd, dinvbu, XWtd, XWbu,
                                          b1td, b1bu, H1td, H1bu);
    // linear2 (+RB, *dinv, bf16) both branches
    k_gemm2<<<2 * NB2, 256, 0, stream>>>(H1td, H1bu, W2td, W2bu, RBtd, RBbu,
                                         batch, dinvtd, dinvbu, XWtd, XWbu);
    // conv2 + relu + pooled segment-sum (H2 eliminated)
    k_g2pool<<<2 * GB, 256, 0, stream>>>(rp_td, csr_td, rp_bu, csr_bu,
                                         dinvtd, dinvbu, XWtd, XWbu,
                                         b2td, b2bu, batch, poolsum);
    // head
    k_final<<<1, 128, 0, stream>>>(poolsum, H1td, H1bu, batch, rooti, fcW, fcb, out);
}